// Round 3
// baseline (1165.954 us; speedup 1.0000x reference)
//
#include <hip/hip_runtime.h>
#include <math.h>

#define PNUM 300000
#define B_ 2
#define D0 144
#define H0 64
#define W0 160
#define C0 32
#define NVOX (B_*D0*H0*W0)   // 2,949,120

#define D1 72
#define H1 32
#define W1 80
#define C1 64
#define N1S (B_*D1*H1*W1)   // 368640

#define D2 36
#define H2 16
#define W2 40
#define N2S (B_*D2*H2*W2)   // 46080

#define D3 18
#define H3 8
#define W3 20
#define N3S (B_*D3*H3*W3)   // 5760

#define D4 9
#define H4 4
#define W4 10
#define N4S (B_*D4*H4*W4)   // 720

#define EPS_ 1e-4f
#define LEAK_ 0.2f

// workspace layout (4-byte element offsets) -- same footprint as round 2 (147.4 MB)
#define OFF_CNT    0                      // NVOX ints
#define OFF_STATS  2949120                // 1024 floats (stats + counters + gcur@643)
#define OFF_START  2950144                // NVOX ints
#define OFF_SORTED 5899264                // 300,000 ints
#define OFF_X1     6199264                // 23,592,960 floats (first NVOX overlaid by cursor)
#define OFF_M1     29792224               // 368,640
#define OFF_X2     30160864               // 5,898,240 (46080*128, couts 96..127 zero)
#define OFF_M2     36059104               // 46,080
#define OFF_X3     36105184               // 737,280
#define OFF_M3     36842464               // 5,760

// ---------------- densify count (int histogram) ----------------
__global__ __launch_bounds__(256) void k_count(const int* __restrict__ coords,
                                               int* __restrict__ cnt) {
  int i = blockIdx.x * 256 + threadIdx.x;
  if (i >= PNUM) return;
  int b = coords[i*4], x = coords[i*4+1], y = coords[i*4+2], z = coords[i*4+3];
  atomicAdd(&cnt[((b*D0 + x)*H0 + y)*W0 + z], 1);
}

// ---------------- slot allocation: block-scan + single ticket atomic ----------------
__global__ __launch_bounds__(256) void k_alloc(const int* __restrict__ cnt,
                                               int* __restrict__ start,
                                               int* __restrict__ cursor,
                                               int* __restrict__ gcur) {
  __shared__ int wsum[4];
  __shared__ int blockBase;
  int t = threadIdx.x;
  int idx0 = blockIdx.x * 1024 + t * 4;
  int4 cv = *(const int4*)(cnt + idx0);
  int c0 = cv.x, c1 = cv.y, c2 = cv.z, c3 = cv.w;
  int tsum = c0 + c1 + c2 + c3;
  int lane = t & 63, wid = t >> 6;
  int incl = tsum;
#pragma unroll
  for (int off = 1; off < 64; off <<= 1) {
    int v = __shfl_up(incl, off);
    if (lane >= off) incl += v;
  }
  if (lane == 63) wsum[wid] = incl;
  __syncthreads();
  if (t == 0) blockBase = atomicAdd(gcur, wsum[0] + wsum[1] + wsum[2] + wsum[3]);
  __syncthreads();
  int base = blockBase;
  for (int w = 0; w < wid; w++) base += wsum[w];
  int st = base + incl - tsum;   // exclusive within block
  start[idx0 + 0] = st; cursor[idx0 + 0] = st; st += c0;
  start[idx0 + 1] = st; cursor[idx0 + 1] = st; st += c1;
  start[idx0 + 2] = st; cursor[idx0 + 2] = st; st += c2;
  start[idx0 + 3] = st; cursor[idx0 + 3] = st;
}

// ---------------- counting-sort scatter of point indices ----------------
__global__ __launch_bounds__(256) void k_scatter(const int* __restrict__ coords,
                                                 int* __restrict__ cursor,
                                                 int* __restrict__ sorted) {
  int i = blockIdx.x * 256 + threadIdx.x;
  if (i >= PNUM) return;
  int b = coords[i*4], x = coords[i*4+1], y = coords[i*4+2], z = coords[i*4+3];
  int v = ((b*D0 + x)*H0 + y)*W0 + z;
  int slot = atomicAdd(&cursor[v], 1);
  sorted[slot] = i;
}

// ---------------- sparse conv1: 1 wave = 1 parent (x8), lane = cout ----------------
// Only ~1.4 active children per active parent -> ~1.16 GFLOP real work vs 12.1 dense.
// No atomics: stride-2/filter-2 means each child has exactly one parent.
// Fuses densify-average, m1 mask, and n1 count.
__global__ __launch_bounds__(256) void k_conv1s(
    const float* __restrict__ feat, const int* __restrict__ sorted,
    const int* __restrict__ cnt, const int* __restrict__ start,
    const float* __restrict__ w1,
    float* __restrict__ x1, float* __restrict__ m1, float* __restrict__ n1) {
  int t = threadIdx.x;
  int lane = t & 63, wv = t >> 6;
  int nact = 0;
  int pbase = blockIdx.x * 32 + wv * 8;
  for (int pi = 0; pi < 8; pi++) {
    int p = pbase + pi;
    int b = p / (D1*H1*W1); int r = p - b*(D1*H1*W1);
    int ox = r / (H1*W1); r -= ox*(H1*W1);
    int oy = r / W1; int oz = r - oy*W1;
    int st_c = 0, n_c = 0;
    if (lane < 8) {
      int v = ((b*D0 + 2*ox + ((lane >> 2) & 1))*H0 + 2*oy + ((lane >> 1) & 1))*W0 + 2*oz + (lane & 1);
      n_c = cnt[v];
      st_c = start[v];
    }
    unsigned long long act = __ballot(n_c > 0);
    float acc = 0.f;
    unsigned long long mm = act;
    while (mm) {   // wave-uniform loop over active children
      int c = (int)__ffsll(mm) - 1; mm &= mm - 1;
      int stc = __shfl(st_c, c);
      int nc  = __shfl(n_c, c);
      float v = feat[(size_t)sorted[stc] * 32 + (lane & 31)];
      for (int j = 1; j < nc; j++)
        v += feat[(size_t)sorted[stc + j] * 32 + (lane & 31)];
      v *= (1.0f / (float)nc);
      const float* wrow = w1 + c * 2048 + lane;   // w1[k=c][ci][co=lane]
#pragma unroll
      for (int ci = 0; ci < 32; ci++)
        acc = fmaf(__shfl(v, ci), wrow[ci * 64], acc);
    }
    x1[(size_t)p * 64 + lane] = acc;   // exact zero at inactive parents
    bool any = (act != 0ULL);
    if (lane == 0) m1[p] = any ? 1.f : 0.f;
    nact += any ? 1 : 0;
  }
  if (lane == 0) atomicAdd(n1, (float)nact);
}

// ---------------- mask downsample (+ active count via ballot) ----------------
template <int DO, int HO, int WO, int DP, int HP, int WP>
__global__ __launch_bounds__(256) void k_mask(const float* __restrict__ prev,
                                              float* __restrict__ mout,
                                              float* __restrict__ nout, int nsites) {
  int s = blockIdx.x * 256 + threadIdx.x;
  bool act = false;
  if (s < nsites) {
    int b = s / (DO*HO*WO); int r = s - b*(DO*HO*WO);
    int ox = r / (HO*WO); r -= ox*(HO*WO);
    int oy = r / WO; int oz = r - oy*WO;
    int base = ((b*DP + 2*ox)*HP + 2*oy)*WP + 2*oz;
#pragma unroll
    for (int ch = 0; ch < 8; ch++) {
      int idx = base + ((ch >> 2) & 1)*HP*WP + ((ch >> 1) & 1)*WP + (ch & 1);
      act |= (prev[idx] > 0.0f);
    }
    mout[s] = act ? 1.0f : 0.0f;
  }
  unsigned long long bal = __ballot(act);
  if ((threadIdx.x & 63) == 0) atomicAdd(nout, (float)__popcll(bal));
}

// ---------------- per-channel sum / sumsq ----------------
template <int CPAD>
__global__ __launch_bounds__(256) void k_stats(const float* __restrict__ x,
                                               float* __restrict__ sum,
                                               float* __restrict__ ssum,
                                               int nsites, int rows) {
  __shared__ float rs[256], rq[256];
  int gid = blockIdx.x * 256 + threadIdx.x;
  int co = gid & (CPAD - 1);
  int row = gid / CPAD;
  float s = 0.f, q = 0.f;
  for (int site = row; site < nsites; site += rows) {
    float v = x[(size_t)site * CPAD + co];
    s += v; q += v * v;
  }
  rs[threadIdx.x] = s; rq[threadIdx.x] = q;
  __syncthreads();
  if (threadIdx.x < CPAD) {
#pragma unroll
    for (int g = 1; g < 256 / CPAD; g++) {
      s += rs[threadIdx.x + g*CPAD]; q += rq[threadIdx.x + g*CPAD];
    }
    atomicAdd(&sum[co], s); atomicAdd(&ssum[co], q);
  }
}

// ---------------- gather-GEMM conv with fused input BN+LeakyReLU+mask ----------------
// block: 32 sites x 128 couts; thread: 4 sites x 4 couts; K chunks of 64 in LDS.
// xs padded to stride 68 -> 4-way bank conflicts on sq-rows eliminated.
template <int CIN_REAL, int CIN_STRIDE, int COUT_REAL,
          int DO, int HO, int WO, int DP, int HP, int WP>
__global__ __launch_bounds__(256) void k_conv(
    const float* __restrict__ xin, const float* __restrict__ mprev,
    const float* __restrict__ Wm, const float* __restrict__ gam,
    const float* __restrict__ bet, const float* __restrict__ ssumv,
    const float* __restrict__ ssqv, const float* __restrict__ ncnt,
    float* __restrict__ xout) {
  const int K = 8 * CIN_REAL;
  __shared__ __align__(16) float xs[32][68];
  __shared__ __align__(16) float ws[64][128];
  __shared__ __align__(16) float sc[CIN_REAL], sh[CIN_REAL];
  __shared__ int   cbase[32][8];
  __shared__ float cmask[32][8];
  int t = threadIdx.x;
  if (t < CIN_REAL) {
    float n = fmaxf(ncnt[0], 1.0f);
    float mean = ssumv[t] / n;
    float var = ssqv[t] / n - mean * mean;
    float s = gam[t] * rsqrtf(var + EPS_);
    sc[t] = s; sh[t] = bet[t] - mean * s;
  }
  {
    int s = t >> 3, ch = t & 7;
    int g = blockIdx.x * 32 + s;
    int b = g / (DO*HO*WO); int r = g - b*(DO*HO*WO);
    int ox = r / (HO*WO); r -= ox*(HO*WO);
    int oy = r / WO; int oz = r - oy*WO;
    int ps = ((b*DP + 2*ox + ((ch >> 2) & 1))*HP + 2*oy + ((ch >> 1) & 1))*WP + 2*oz + (ch & 1);
    cbase[s][ch] = ps * CIN_STRIDE;
    cmask[s][ch] = mprev[ps];
  }
  int cq = t & 31, sq = t >> 5;
  float4 acc[4] = {{0,0,0,0},{0,0,0,0},{0,0,0,0},{0,0,0,0}};
  for (int k0 = 0; k0 < K; k0 += 64) {
    __syncthreads();
    // stage x: 512 float4 (32 sites x 16 quads), BN+LeakyReLU+mask fused
#pragma unroll
    for (int ii = 0; ii < 2; ii++) {
      int idx = t + ii*256;
      int s = idx >> 4, q = idx & 15;
      int k = k0 + q*4;
      int ch = k / CIN_REAL;
      int ci = k - ch*CIN_REAL;
      float4 v = *(const float4*)(xin + cbase[s][ch] + ci);
      float4 scv = *(const float4*)&sc[ci];
      float4 shv = *(const float4*)&sh[ci];
      float msk = cmask[s][ch];
      v.x = v.x*scv.x + shv.x; v.x = (v.x > 0.f ? v.x : LEAK_*v.x) * msk;
      v.y = v.y*scv.y + shv.y; v.y = (v.y > 0.f ? v.y : LEAK_*v.y) * msk;
      v.z = v.z*scv.z + shv.z; v.z = (v.z > 0.f ? v.z : LEAK_*v.z) * msk;
      v.w = v.w*scv.w + shv.w; v.w = (v.w > 0.f ? v.w : LEAK_*v.w) * msk;
      *(float4*)&xs[s][q*4] = v;
    }
    // stage w: 2048 float4 (64 k x 32 quads)
#pragma unroll
    for (int ii = 0; ii < 8; ii++) {
      int idx = t + ii*256;
      int kk = idx >> 5, c4 = idx & 31;
      int co = c4 * 4;
      float4 w;
      if (co < COUT_REAL) w = *(const float4*)(Wm + (size_t)(k0 + kk)*COUT_REAL + co);
      else w = make_float4(0.f, 0.f, 0.f, 0.f);
      *(float4*)&ws[kk][co] = w;
    }
    __syncthreads();
#pragma unroll
    for (int kk = 0; kk < 64; kk += 4) {
      float4 w0 = *(const float4*)&ws[kk    ][cq*4];
      float4 w1v = *(const float4*)&ws[kk + 1][cq*4];
      float4 w2v = *(const float4*)&ws[kk + 2][cq*4];
      float4 w3v = *(const float4*)&ws[kk + 3][cq*4];
#pragma unroll
      for (int j = 0; j < 4; j++) {
        float4 xv = *(const float4*)&xs[sq + 8*j][kk];
        acc[j].x += xv.x*w0.x + xv.y*w1v.x + xv.z*w2v.x + xv.w*w3v.x;
        acc[j].y += xv.x*w0.y + xv.y*w1v.y + xv.z*w2v.y + xv.w*w3v.y;
        acc[j].z += xv.x*w0.z + xv.y*w1v.z + xv.z*w2v.z + xv.w*w3v.z;
        acc[j].w += xv.x*w0.w + xv.y*w1v.w + xv.z*w2v.w + xv.w*w3v.w;
      }
    }
  }
#pragma unroll
  for (int j = 0; j < 4; j++) {
    int g = blockIdx.x * 32 + sq + 8*j;
    *(float4*)&xout[(size_t)g * 128 + cq*4] = acc[j];
  }
}

// ---------------- final conv (cout=1) + sigmoid + mask ----------------
__global__ __launch_bounds__(256) void k_final(
    const float* __restrict__ x3, const float* __restrict__ m3,
    const float* __restrict__ w4, const float* __restrict__ gam,
    const float* __restrict__ bet, const float* __restrict__ ssumv,
    const float* __restrict__ ssqv, const float* __restrict__ ncnt,
    float* __restrict__ out) {
  __shared__ float sc[128], sh[128];
  __shared__ int cb[8];
  __shared__ float msk[8];
  __shared__ float red[256];
  int t = threadIdx.x;
  if (t < 128) {
    float n = fmaxf(ncnt[0], 1.0f);
    float mean = ssumv[t] / n;
    float var = ssqv[t] / n - mean * mean;
    float s = gam[t] * rsqrtf(var + EPS_);
    sc[t] = s; sh[t] = bet[t] - mean * s;
  }
  int g = blockIdx.x;
  int b = g / (D4*H4*W4); int r = g - b*(D4*H4*W4);
  int ox = r / (H4*W4); r -= ox*(H4*W4);
  int oy = r / W4; int oz = r - oy*W4;
  if (t < 8) {
    int ps = ((b*D3 + 2*ox + ((t >> 2) & 1))*H3 + 2*oy + ((t >> 1) & 1))*W3 + 2*oz + (t & 1);
    cb[t] = ps * 128;
    msk[t] = m3[ps];
  }
  __syncthreads();
  float acc = 0.f;
#pragma unroll
  for (int ii = 0; ii < 4; ii++) {
    int k = t + ii*256;
    int ch = k >> 7, ci = k & 127;
    float v = x3[cb[ch] + ci];
    v = v * sc[ci] + sh[ci];
    v = (v > 0.f ? v : LEAK_ * v) * msk[ch];
    acc += v * w4[k];
  }
  red[t] = acc;
  __syncthreads();
  if (t < 128) red[t] += red[t + 128];
  __syncthreads();
  if (t < 64) {
    float v = red[t] + red[t + 64];
#pragma unroll
    for (int off = 32; off > 0; off >>= 1) v += __shfl_down(v, off);
    if (t == 0) {
      float any = (msk[0] + msk[1] + msk[2] + msk[3] + msk[4] + msk[5] + msk[6] + msk[7]) > 0.f ? 1.f : 0.f;
      out[g] = any / (1.0f + expf(-v));
    }
  }
}

extern "C" void kernel_launch(void* const* d_in, const int* in_sizes, int n_in,
                              void* d_out, int out_size, void* d_ws, size_t ws_size,
                              hipStream_t stream) {
  (void)in_sizes; (void)n_in; (void)out_size; (void)ws_size;
  const float* feat = (const float*)d_in[0];
  const int*   crd  = (const int*)d_in[1];
  const float* w1 = (const float*)d_in[2];
  const float* g1 = (const float*)d_in[3];
  const float* b1 = (const float*)d_in[4];
  const float* w2 = (const float*)d_in[5];
  const float* g2 = (const float*)d_in[6];
  const float* b2 = (const float*)d_in[7];
  const float* w3 = (const float*)d_in[8];
  const float* g3 = (const float*)d_in[9];
  const float* b3 = (const float*)d_in[10];
  const float* w4 = (const float*)d_in[11];
  float* out = (float*)d_out;
  float* ws  = (float*)d_ws;

  int*   cnt    = (int*)(ws + OFF_CNT);
  float* st     = ws + OFF_STATS;   // s1@0 q1@64 s2@128 q2@256 s3@384 q3@512 n1@640 n2@641 n3@642 gcur@643
  int*   start  = (int*)(ws + OFF_START);
  int*   sorted = (int*)(ws + OFF_SORTED);
  float* x1     = ws + OFF_X1;
  int*   cursor = (int*)(ws + OFF_X1);    // overlays x1 (dead before conv1s writes)
  float* m1     = ws + OFF_M1;
  float* x2     = ws + OFF_X2;
  float* m2     = ws + OFF_M2;
  float* x3     = ws + OFF_X3;
  float* m3     = ws + OFF_M3;

  // zero cnt + stats (contiguous prefix)
  hipMemsetAsync(d_ws, 0, (size_t)(OFF_STATS + 1024) * sizeof(float), stream);

  k_count<<<(PNUM + 255) / 256, 256, 0, stream>>>(crd, cnt);
  k_alloc<<<NVOX / 1024, 256, 0, stream>>>(cnt, start, cursor, (int*)(st + 643));
  k_scatter<<<(PNUM + 255) / 256, 256, 0, stream>>>(crd, cursor, sorted);
  k_conv1s<<<N1S / 32, 256, 0, stream>>>(feat, sorted, cnt, start, w1, x1, m1, st + 640);
  k_stats<64><<<360, 256, 0, stream>>>(x1, st + 0, st + 64, N1S, 360 * 256 / 64);
  k_mask<D2,H2,W2, D1,H1,W1><<<N2S / 256, 256, 0, stream>>>(m1, m2, st + 641, N2S);
  k_conv<64, 64, 96, D2,H2,W2, D1,H1,W1><<<N2S / 32, 256, 0, stream>>>(
      x1, m1, w2, g1, b1, st + 0, st + 64, st + 640, x2);
  k_stats<128><<<180, 256, 0, stream>>>(x2, st + 128, st + 256, N2S, 180 * 256 / 128);
  k_mask<D3,H3,W3, D2,H2,W2><<<(N3S + 255) / 256, 256, 0, stream>>>(m2, m3, st + 642, N3S);
  k_conv<96, 128, 128, D3,H3,W3, D2,H2,W2><<<N3S / 32, 256, 0, stream>>>(
      x2, m2, w3, g2, b2, st + 128, st + 256, st + 641, x3);
  k_stats<128><<<45, 256, 0, stream>>>(x3, st + 384, st + 512, N3S, 45 * 256 / 128);
  k_final<<<N4S, 256, 0, stream>>>(x3, m3, w4, g3, b3, st + 384, st + 512, st + 642, out);
}

// Round 4
// 929.656 us; speedup vs baseline: 1.2542x; 1.2542x over previous
//
#include <hip/hip_runtime.h>
#include <math.h>

#define PNUM 300000
#define B_ 2
#define D0 144
#define H0 64
#define W0 160
#define C0 32
#define NVOX (B_*D0*H0*W0)   // 2,949,120 (= 368640 parents * 8 octants)

#define D1 72
#define H1 32
#define W1 80
#define C1 64
#define N1S (B_*D1*H1*W1)   // 368640

#define D2 36
#define H2 16
#define W2 40
#define N2S (B_*D2*H2*W2)   // 46080

#define D3 18
#define H3 8
#define W3 20
#define N3S (B_*D3*H3*W3)   // 5760

#define D4 9
#define H4 4
#define W4 10
#define N4S (B_*D4*H4*W4)   // 720

#define EPS_ 1e-4f
#define LEAK_ 0.2f

// workspace layout (4-byte element offsets) -- 188.5 MB
#define OFF_CNT    0                      // NVOX ints  (key = parent*8+octant)
#define OFF_STATS  2949120                // 1024 floats/ints
#define OFF_START  2950144                // NVOX ints
#define OFF_SORTED 5899264                // 300,000 ints
#define OFF_AKLIST 6199264                // 300,000 ints (active keys)
#define OFF_PLIST  6499264                // 368,640 ints (active parents)
#define OFF_AFEAT  6867904                // 9,600,000 floats (avg feat per slot-region)
#define OFF_X1     16467904               // 23,592,960 floats (cursor overlays head)
#define OFF_M1     40060864               // 368,640
#define OFF_X2     40429504               // 5,898,240 (46080*128, couts 96..127 zero)
#define OFF_M2     46327744               // 46,080
#define OFF_X3     46373824               // 737,280
#define OFF_M3     47111104               // 5,760
// total 47,116,864 * 4B

__device__ __forceinline__ int voxkey(int b, int x, int y, int z) {
  int p = ((b*D1 + (x >> 1))*H1 + (y >> 1))*W1 + (z >> 1);
  int oct = ((x & 1) << 2) | ((y & 1) << 1) | (z & 1);
  return p*8 + oct;
}

// ---------------- densify count (int histogram, parent-grouped keys) ----------------
__global__ __launch_bounds__(256) void k_count(const int* __restrict__ coords,
                                               int* __restrict__ cnt) {
  int i = blockIdx.x * 256 + threadIdx.x;
  if (i >= PNUM) return;
  int4 c = *(const int4*)(coords + i*4);
  atomicAdd(&cnt[voxkey(c.x, c.y, c.z, c.w)], 1);
}

// ---------------- slot allocation: block-scan + single ticket atomic ----------------
__global__ __launch_bounds__(256) void k_alloc(const int* __restrict__ cnt,
                                               int* __restrict__ start,
                                               int* __restrict__ cursor,
                                               int* __restrict__ gcur) {
  __shared__ int wsum[4];
  __shared__ int blockBase;
  int t = threadIdx.x;
  int idx0 = blockIdx.x * 1024 + t * 4;
  int4 cv = *(const int4*)(cnt + idx0);
  int c0 = cv.x, c1 = cv.y, c2 = cv.z, c3 = cv.w;
  int tsum = c0 + c1 + c2 + c3;
  int lane = t & 63, wid = t >> 6;
  int incl = tsum;
#pragma unroll
  for (int off = 1; off < 64; off <<= 1) {
    int v = __shfl_up(incl, off);
    if (lane >= off) incl += v;
  }
  if (lane == 63) wsum[wid] = incl;
  __syncthreads();
  if (t == 0) blockBase = atomicAdd(gcur, wsum[0] + wsum[1] + wsum[2] + wsum[3]);
  __syncthreads();
  int base = blockBase;
  for (int w = 0; w < wid; w++) base += wsum[w];
  int st = base + incl - tsum;   // exclusive within block
  start[idx0 + 0] = st; cursor[idx0 + 0] = st; st += c0;
  start[idx0 + 1] = st; cursor[idx0 + 1] = st; st += c1;
  start[idx0 + 2] = st; cursor[idx0 + 2] = st; st += c2;
  start[idx0 + 3] = st; cursor[idx0 + 3] = st;
}

// ---------------- counting-sort scatter of point indices ----------------
__global__ __launch_bounds__(256) void k_scatter(const int* __restrict__ coords,
                                                 int* __restrict__ cursor,
                                                 int* __restrict__ sorted) {
  int i = blockIdx.x * 256 + threadIdx.x;
  if (i >= PNUM) return;
  int4 c = *(const int4*)(coords + i*4);
  int slot = atomicAdd(&cursor[voxkey(c.x, c.y, c.z, c.w)], 1);
  sorted[slot] = i;
}

// ---------------- active-parent / active-key compaction + m1 + n1 ----------------
__global__ __launch_bounds__(256) void k_plist(const int* __restrict__ cnt,
                                               float* __restrict__ m1,
                                               float* __restrict__ n1f,
                                               int* __restrict__ plist,
                                               int* __restrict__ aklist,
                                               int* __restrict__ nactp,
                                               int* __restrict__ nactk) {
  int p = blockIdx.x * 256 + threadIdx.x;   // grid covers exactly N1S
  int lane = threadIdx.x & 63;
  const int4* c4 = (const int4*)(cnt + (size_t)p*8);
  int4 a = c4[0], b = c4[1];
  int cn[8] = {a.x, a.y, a.z, a.w, b.x, b.y, b.z, b.w};
  int ck = 0;
#pragma unroll
  for (int i = 0; i < 8; i++) ck += (cn[i] > 0) ? 1 : 0;
  bool pa = ck > 0;
  m1[p] = pa ? 1.f : 0.f;
  unsigned long long bal = __ballot(pa);
  int pcnt = __popcll(bal);
  int pbase = 0;
  if (lane == 0) pbase = atomicAdd(nactp, pcnt);
  pbase = __shfl(pbase, 0);
  if (pa) plist[pbase + __popcll(bal & ((1ull << lane) - 1ull))] = p;
  int incl = ck;
#pragma unroll
  for (int o = 1; o < 64; o <<= 1) {
    int v = __shfl_up(incl, o);
    if (lane >= o) incl += v;
  }
  int tot = __shfl(incl, 63);
  int kbase = 0;
  if (lane == 0) kbase = atomicAdd(nactk, tot);
  kbase = __shfl(kbase, 0);
  int off = kbase + incl - ck;
#pragma unroll
  for (int i = 0; i < 8; i++)
    if (cn[i] > 0) aklist[off++] = p*8 + i;
  if (lane == 0) atomicAdd(n1f, (float)pcnt);
}

// ---------------- duplicate-averaging into compact afeat (8 threads/key) ----------------
__global__ __launch_bounds__(256) void k_avg(const float* __restrict__ feat,
                                             const int* __restrict__ sorted,
                                             const int* __restrict__ cnt,
                                             const int* __restrict__ start,
                                             const int* __restrict__ aklist,
                                             const int* __restrict__ nactk,
                                             float* __restrict__ afeat) {
  int gid = blockIdx.x * 256 + threadIdx.x;
  int j = gid >> 3;
  if (j >= nactk[0]) return;
  int key = aklist[j];
  int c = cnt[key];
  int s0 = start[key];
  int q = (gid & 7) * 4;
  float4 acc = {0.f, 0.f, 0.f, 0.f};
  for (int i = 0; i < c; i++) {
    float4 v = *(const float4*)(feat + (size_t)sorted[s0 + i] * 32 + q);
    acc.x += v.x; acc.y += v.y; acc.z += v.z; acc.w += v.w;
  }
  float inv = 1.f / (float)c;
  acc.x *= inv; acc.y *= inv; acc.z *= inv; acc.w *= inv;
  *(float4*)(afeat + (size_t)s0 * 32 + q) = acc;
}

// ---------------- conv1 GEMM over active parents: 32 parents x 64 couts ----------------
__global__ __launch_bounds__(256) void k_conv1p(
    const float* __restrict__ afeat, const int* __restrict__ cnt,
    const int* __restrict__ start, const int* __restrict__ plist,
    const int* __restrict__ nactp, const float* __restrict__ w1,
    float* __restrict__ x1) {
  int nact = nactp[0];
  int tb = blockIdx.x;
  if (tb * 32 >= nact) return;
  __shared__ __align__(16) float xs[32][68];
  __shared__ __align__(16) float wsm[64][64];
  __shared__ int pl[32];
  __shared__ int cst[32][8];
  __shared__ int ccn[32][8];
  int t = threadIdx.x;
  {
    int s = t >> 3, ch = t & 7;
    int gsite = tb * 32 + s;
    bool valid = gsite < nact;
    int p = valid ? plist[gsite] : 0;
    if (ch == 0) pl[s] = p;
    int key = p*8 + ch;
    int c = valid ? cnt[key] : 0;
    ccn[s][ch] = c;
    cst[s][ch] = (c > 0) ? start[key] : 0;
  }
  int cq = t & 15, sq = t >> 4;
  float4 acc[2] = {{0,0,0,0},{0,0,0,0}};
  for (int k0 = 0; k0 < 256; k0 += 64) {
    __syncthreads();
    // stage xs: 32 sites x 16 quads (512 float4)
#pragma unroll
    for (int ii = 0; ii < 2; ii++) {
      int idx = t + ii*256;
      int s = idx >> 4, q = idx & 15;
      int k = k0 + q*4;
      int ch = k >> 5, ci = k & 31;
      int c = ccn[s][ch];
      float4 v = {0.f, 0.f, 0.f, 0.f};
      if (c > 0) v = *(const float4*)(afeat + (size_t)cst[s][ch] * 32 + ci);
      *(float4*)&xs[s][q*4] = v;
    }
    // stage ws: 64 k x 16 quads (1024 float4); w1 flat is [k=256][co=64]
#pragma unroll
    for (int ii = 0; ii < 4; ii++) {
      int idx = t + ii*256;
      int kk = idx >> 4, c4 = (idx & 15) * 4;
      *(float4*)&wsm[kk][c4] = *(const float4*)(w1 + (size_t)(k0 + kk)*64 + c4);
    }
    __syncthreads();
#pragma unroll
    for (int kk = 0; kk < 64; kk += 4) {
      float4 w0 = *(const float4*)&wsm[kk    ][cq*4];
      float4 w1v = *(const float4*)&wsm[kk + 1][cq*4];
      float4 w2v = *(const float4*)&wsm[kk + 2][cq*4];
      float4 w3v = *(const float4*)&wsm[kk + 3][cq*4];
#pragma unroll
      for (int j = 0; j < 2; j++) {
        float4 xv = *(const float4*)&xs[sq + 16*j][kk];
        acc[j].x += xv.x*w0.x + xv.y*w1v.x + xv.z*w2v.x + xv.w*w3v.x;
        acc[j].y += xv.x*w0.y + xv.y*w1v.y + xv.z*w2v.y + xv.w*w3v.y;
        acc[j].z += xv.x*w0.z + xv.y*w1v.z + xv.z*w2v.z + xv.w*w3v.z;
        acc[j].w += xv.x*w0.w + xv.y*w1v.w + xv.z*w2v.w + xv.w*w3v.w;
      }
    }
  }
#pragma unroll
  for (int j = 0; j < 2; j++) {
    int site = sq + 16*j;
    int gsite = tb * 32 + site;
    if (gsite < nact)
      *(float4*)&x1[(size_t)pl[site] * 64 + cq*4] = acc[j];
  }
}

// ---------------- mask downsample (+ active count via ballot) ----------------
template <int DO, int HO, int WO, int DP, int HP, int WP>
__global__ __launch_bounds__(256) void k_mask(const float* __restrict__ prev,
                                              float* __restrict__ mout,
                                              float* __restrict__ nout, int nsites) {
  int s = blockIdx.x * 256 + threadIdx.x;
  bool act = false;
  if (s < nsites) {
    int b = s / (DO*HO*WO); int r = s - b*(DO*HO*WO);
    int ox = r / (HO*WO); r -= ox*(HO*WO);
    int oy = r / WO; int oz = r - oy*WO;
    int base = ((b*DP + 2*ox)*HP + 2*oy)*WP + 2*oz;
#pragma unroll
    for (int ch = 0; ch < 8; ch++) {
      int idx = base + ((ch >> 2) & 1)*HP*WP + ((ch >> 1) & 1)*WP + (ch & 1);
      act |= (prev[idx] > 0.0f);
    }
    mout[s] = act ? 1.0f : 0.0f;
  }
  unsigned long long bal = __ballot(act);
  if ((threadIdx.x & 63) == 0) atomicAdd(nout, (float)__popcll(bal));
}

// ---------------- per-channel sum / sumsq ----------------
template <int CPAD>
__global__ __launch_bounds__(256) void k_stats(const float* __restrict__ x,
                                               float* __restrict__ sum,
                                               float* __restrict__ ssum,
                                               int nsites, int rows) {
  __shared__ float rs[256], rq[256];
  int gid = blockIdx.x * 256 + threadIdx.x;
  int co = gid & (CPAD - 1);
  int row = gid / CPAD;
  float s = 0.f, q = 0.f;
  for (int site = row; site < nsites; site += rows) {
    float v = x[(size_t)site * CPAD + co];
    s += v; q += v * v;
  }
  rs[threadIdx.x] = s; rq[threadIdx.x] = q;
  __syncthreads();
  if (threadIdx.x < CPAD) {
#pragma unroll
    for (int g = 1; g < 256 / CPAD; g++) {
      s += rs[threadIdx.x + g*CPAD]; q += rq[threadIdx.x + g*CPAD];
    }
    atomicAdd(&sum[co], s); atomicAdd(&ssum[co], q);
  }
}

// ---------------- gather-GEMM conv with fused input BN+LeakyReLU+mask ----------------
template <int CIN_REAL, int CIN_STRIDE, int COUT_REAL,
          int DO, int HO, int WO, int DP, int HP, int WP>
__global__ __launch_bounds__(256) void k_conv(
    const float* __restrict__ xin, const float* __restrict__ mprev,
    const float* __restrict__ Wm, const float* __restrict__ gam,
    const float* __restrict__ bet, const float* __restrict__ ssumv,
    const float* __restrict__ ssqv, const float* __restrict__ ncnt,
    float* __restrict__ xout) {
  const int K = 8 * CIN_REAL;
  __shared__ __align__(16) float xs[32][68];
  __shared__ __align__(16) float ws[64][128];
  __shared__ __align__(16) float sc[CIN_REAL], sh[CIN_REAL];
  __shared__ int   cbase[32][8];
  __shared__ float cmask[32][8];
  int t = threadIdx.x;
  if (t < CIN_REAL) {
    float n = fmaxf(ncnt[0], 1.0f);
    float mean = ssumv[t] / n;
    float var = ssqv[t] / n - mean * mean;
    float s = gam[t] * rsqrtf(var + EPS_);
    sc[t] = s; sh[t] = bet[t] - mean * s;
  }
  {
    int s = t >> 3, ch = t & 7;
    int g = blockIdx.x * 32 + s;
    int b = g / (DO*HO*WO); int r = g - b*(DO*HO*WO);
    int ox = r / (HO*WO); r -= ox*(HO*WO);
    int oy = r / WO; int oz = r - oy*WO;
    int ps = ((b*DP + 2*ox + ((ch >> 2) & 1))*HP + 2*oy + ((ch >> 1) & 1))*WP + 2*oz + (ch & 1);
    cbase[s][ch] = ps * CIN_STRIDE;
    cmask[s][ch] = mprev[ps];
  }
  int cq = t & 31, sq = t >> 5;
  float4 acc[4] = {{0,0,0,0},{0,0,0,0},{0,0,0,0},{0,0,0,0}};
  for (int k0 = 0; k0 < K; k0 += 64) {
    __syncthreads();
#pragma unroll
    for (int ii = 0; ii < 2; ii++) {
      int idx = t + ii*256;
      int s = idx >> 4, q = idx & 15;
      int k = k0 + q*4;
      int ch = k / CIN_REAL;
      int ci = k - ch*CIN_REAL;
      float4 v = *(const float4*)(xin + cbase[s][ch] + ci);
      float4 scv = *(const float4*)&sc[ci];
      float4 shv = *(const float4*)&sh[ci];
      float msk = cmask[s][ch];
      v.x = v.x*scv.x + shv.x; v.x = (v.x > 0.f ? v.x : LEAK_*v.x) * msk;
      v.y = v.y*scv.y + shv.y; v.y = (v.y > 0.f ? v.y : LEAK_*v.y) * msk;
      v.z = v.z*scv.z + shv.z; v.z = (v.z > 0.f ? v.z : LEAK_*v.z) * msk;
      v.w = v.w*scv.w + shv.w; v.w = (v.w > 0.f ? v.w : LEAK_*v.w) * msk;
      *(float4*)&xs[s][q*4] = v;
    }
#pragma unroll
    for (int ii = 0; ii < 8; ii++) {
      int idx = t + ii*256;
      int kk = idx >> 5, c4 = idx & 31;
      int co = c4 * 4;
      float4 w;
      if (co < COUT_REAL) w = *(const float4*)(Wm + (size_t)(k0 + kk)*COUT_REAL + co);
      else w = make_float4(0.f, 0.f, 0.f, 0.f);
      *(float4*)&ws[kk][co] = w;
    }
    __syncthreads();
#pragma unroll
    for (int kk = 0; kk < 64; kk += 4) {
      float4 w0 = *(const float4*)&ws[kk    ][cq*4];
      float4 w1v = *(const float4*)&ws[kk + 1][cq*4];
      float4 w2v = *(const float4*)&ws[kk + 2][cq*4];
      float4 w3v = *(const float4*)&ws[kk + 3][cq*4];
#pragma unroll
      for (int j = 0; j < 4; j++) {
        float4 xv = *(const float4*)&xs[sq + 8*j][kk];
        acc[j].x += xv.x*w0.x + xv.y*w1v.x + xv.z*w2v.x + xv.w*w3v.x;
        acc[j].y += xv.x*w0.y + xv.y*w1v.y + xv.z*w2v.y + xv.w*w3v.y;
        acc[j].z += xv.x*w0.z + xv.y*w1v.z + xv.z*w2v.z + xv.w*w3v.z;
        acc[j].w += xv.x*w0.w + xv.y*w1v.w + xv.z*w2v.w + xv.w*w3v.w;
      }
    }
  }
#pragma unroll
  for (int j = 0; j < 4; j++) {
    int g = blockIdx.x * 32 + sq + 8*j;
    *(float4*)&xout[(size_t)g * 128 + cq*4] = acc[j];
  }
}

// ---------------- final conv (cout=1) + sigmoid + mask ----------------
__global__ __launch_bounds__(256) void k_final(
    const float* __restrict__ x3, const float* __restrict__ m3,
    const float* __restrict__ w4, const float* __restrict__ gam,
    const float* __restrict__ bet, const float* __restrict__ ssumv,
    const float* __restrict__ ssqv, const float* __restrict__ ncnt,
    float* __restrict__ out) {
  __shared__ float sc[128], sh[128];
  __shared__ int cb[8];
  __shared__ float msk[8];
  __shared__ float red[256];
  int t = threadIdx.x;
  if (t < 128) {
    float n = fmaxf(ncnt[0], 1.0f);
    float mean = ssumv[t] / n;
    float var = ssqv[t] / n - mean * mean;
    float s = gam[t] * rsqrtf(var + EPS_);
    sc[t] = s; sh[t] = bet[t] - mean * s;
  }
  int g = blockIdx.x;
  int b = g / (D4*H4*W4); int r = g - b*(D4*H4*W4);
  int ox = r / (H4*W4); r -= ox*(H4*W4);
  int oy = r / W4; int oz = r - oy*W4;
  if (t < 8) {
    int ps = ((b*D3 + 2*ox + ((t >> 2) & 1))*H3 + 2*oy + ((t >> 1) & 1))*W3 + 2*oz + (t & 1);
    cb[t] = ps * 128;
    msk[t] = m3[ps];
  }
  __syncthreads();
  float acc = 0.f;
#pragma unroll
  for (int ii = 0; ii < 4; ii++) {
    int k = t + ii*256;
    int ch = k >> 7, ci = k & 127;
    float v = x3[cb[ch] + ci];
    v = v * sc[ci] + sh[ci];
    v = (v > 0.f ? v : LEAK_ * v) * msk[ch];
    acc += v * w4[k];
  }
  red[t] = acc;
  __syncthreads();
  if (t < 128) red[t] += red[t + 128];
  __syncthreads();
  if (t < 64) {
    float v = red[t] + red[t + 64];
#pragma unroll
    for (int off = 32; off > 0; off >>= 1) v += __shfl_down(v, off);
    if (t == 0) {
      float any = (msk[0] + msk[1] + msk[2] + msk[3] + msk[4] + msk[5] + msk[6] + msk[7]) > 0.f ? 1.f : 0.f;
      out[g] = any / (1.0f + expf(-v));
    }
  }
}

extern "C" void kernel_launch(void* const* d_in, const int* in_sizes, int n_in,
                              void* d_out, int out_size, void* d_ws, size_t ws_size,
                              hipStream_t stream) {
  (void)in_sizes; (void)n_in; (void)out_size; (void)ws_size;
  const float* feat = (const float*)d_in[0];
  const int*   crd  = (const int*)d_in[1];
  const float* w1 = (const float*)d_in[2];
  const float* g1 = (const float*)d_in[3];
  const float* b1 = (const float*)d_in[4];
  const float* w2 = (const float*)d_in[5];
  const float* g2 = (const float*)d_in[6];
  const float* b2 = (const float*)d_in[7];
  const float* w3 = (const float*)d_in[8];
  const float* g3 = (const float*)d_in[9];
  const float* b3 = (const float*)d_in[10];
  const float* w4 = (const float*)d_in[11];
  float* out = (float*)d_out;
  float* ws  = (float*)d_ws;

  int*   cnt    = (int*)(ws + OFF_CNT);
  float* st     = ws + OFF_STATS;   // s1@0 q1@64 s2@128 q2@256 s3@384 q3@512 n1@640 n2@641 n3@642 gcur@643 nactp@644 nactk@645
  int*   start  = (int*)(ws + OFF_START);
  int*   sorted = (int*)(ws + OFF_SORTED);
  int*   aklist = (int*)(ws + OFF_AKLIST);
  int*   plist  = (int*)(ws + OFF_PLIST);
  float* afeat  = ws + OFF_AFEAT;
  float* x1     = ws + OFF_X1;
  int*   cursor = (int*)(ws + OFF_X1);    // overlays x1 head; dead before x1 memset
  float* m1     = ws + OFF_M1;
  float* x2     = ws + OFF_X2;
  float* m2     = ws + OFF_M2;
  float* x3     = ws + OFF_X3;
  float* m3     = ws + OFF_M3;

  // zero cnt + stats/counters (contiguous prefix)
  hipMemsetAsync(d_ws, 0, (size_t)(OFF_STATS + 1024) * sizeof(float), stream);

  k_count<<<(PNUM + 255) / 256, 256, 0, stream>>>(crd, cnt);
  k_alloc<<<NVOX / 1024, 256, 0, stream>>>(cnt, start, cursor, (int*)(st + 643));
  k_scatter<<<(PNUM + 255) / 256, 256, 0, stream>>>(crd, cursor, sorted);
  k_plist<<<N1S / 256, 256, 0, stream>>>(cnt, m1, st + 640, plist, aklist,
                                         (int*)(st + 644), (int*)(st + 645));
  k_avg<<<(PNUM * 8) / 256 + 1, 256, 0, stream>>>(feat, sorted, cnt, start, aklist,
                                                  (const int*)(st + 645), afeat);
  hipMemsetAsync(x1, 0, (size_t)N1S * 64 * sizeof(float), stream);
  k_conv1p<<<N1S / 32, 256, 0, stream>>>(afeat, cnt, start, plist,
                                         (const int*)(st + 644), w1, x1);
  k_stats<64><<<360, 256, 0, stream>>>(x1, st + 0, st + 64, N1S, 360 * 256 / 64);
  k_mask<D2,H2,W2, D1,H1,W1><<<N2S / 256, 256, 0, stream>>>(m1, m2, st + 641, N2S);
  k_conv<64, 64, 96, D2,H2,W2, D1,H1,W1><<<N2S / 32, 256, 0, stream>>>(
      x1, m1, w2, g1, b1, st + 0, st + 64, st + 640, x2);
  k_stats<128><<<180, 256, 0, stream>>>(x2, st + 128, st + 256, N2S, 180 * 256 / 128);
  k_mask<D3,H3,W3, D2,H2,W2><<<(N3S + 255) / 256, 256, 0, stream>>>(m2, m3, st + 642, N3S);
  k_conv<96, 128, 128, D3,H3,W3, D2,H2,W2><<<N3S / 32, 256, 0, stream>>>(
      x2, m2, w3, g2, b2, st + 128, st + 256, st + 641, x3);
  k_stats<128><<<45, 256, 0, stream>>>(x3, st + 384, st + 512, N3S, 45 * 256 / 128);
  k_final<<<N4S, 256, 0, stream>>>(x3, m3, w4, g3, b3, st + 384, st + 512, st + 642, out);
}

// Round 5
// 666.900 us; speedup vs baseline: 1.7483x; 1.3940x over previous
//
#include <hip/hip_runtime.h>
#include <math.h>

#define PNUM 300000
#define B_ 2
#define D0 144
#define H0 64
#define W0 160
#define NVOX (B_*D0*H0*W0)   // 2,949,120

#define D1 72
#define H1 32
#define W1 80
#define N1S (B_*D1*H1*W1)   // 368640

#define D2 36
#define H2 16
#define W2 40
#define N2S (B_*D2*H2*W2)   // 46080

#define D3 18
#define H3 8
#define W3 20
#define N3S (B_*D3*H3*W3)   // 5760

#define D4 9
#define H4 4
#define W4 10
#define N4S (B_*D4*H4*W4)   // 720

#define EPS_ 1e-4f
#define LEAK_ 0.2f

typedef __attribute__((ext_vector_type(8))) short v8s;   // 8 bf16 (4 VGPRs)
typedef __attribute__((ext_vector_type(4))) float v4f;

typedef unsigned short ushort_t;
typedef unsigned int uint_t;

__device__ __forceinline__ ushort_t f2b(float f) {
  union { float f; uint_t u; } x; x.f = f;
  uint_t r = x.u + 0x7FFFu + ((x.u >> 16) & 1u);   // RNE
  return (ushort_t)(r >> 16);
}
__device__ __forceinline__ float b2f(ushort_t h) {
  union { uint_t u; float f; } x; x.u = ((uint_t)h) << 16; return x.f;
}

// workspace layout (4-byte word offsets) -- ~109 MB
#define OFF_CNT     0                     // NVOX ints (key = parent*8+octant)
#define OFF_STATS   2949120               // 1024: s1@0 q1@64 s2@128 q2@256 s3@384 q3@512 n1@640 n2@641 n3@642 gcur@643 nactp@644 nactk@645
#define OFF_START   2950144               // NVOX ints
#define OFF_SORTED  5899264               // 300,000 ints
#define OFF_AKLIST  6199264               // 300,000 ints
#define OFF_PLIST   6499264               // 368,640 ints
#define OFF_WT1     6867904               // 16,384 bf16 = 8,192 w
#define OFF_WT2     6876096               // 65,536 bf16 = 32,768 w
#define OFF_WT3     6908864               // 131,072 bf16 = 65,536 w
#define OFF_AFEATB  6974400               // 9.6M bf16 = 4.8M w
#define OFF_X1B     11774400              // 23.59M bf16 = 11,796,480 w (cursor overlays head)
#define OFF_X2B     23570880              // 5.898M bf16 = 2,949,120 w
#define OFF_X3B     26520000              // 737,280 bf16 = 368,640 w
#define OFF_M1      26888640              // 368,640 f32
#define OFF_M2      27257280              // 46,080
#define OFF_M3      27303360              // 5,760

__device__ __forceinline__ int voxkey(int b, int x, int y, int z) {
  int p = ((b*D1 + (x >> 1))*H1 + (y >> 1))*W1 + (z >> 1);
  int oct = ((x & 1) << 2) | ((y & 1) << 1) | (z & 1);
  return p*8 + oct;
}

// ---------------- densify count ----------------
__global__ __launch_bounds__(256) void k_count(const int* __restrict__ coords,
                                               int* __restrict__ cnt) {
  int i = blockIdx.x * 256 + threadIdx.x;
  if (i >= PNUM) return;
  int4 c = *(const int4*)(coords + i*4);
  atomicAdd(&cnt[voxkey(c.x, c.y, c.z, c.w)], 1);
}

// ---------------- slot allocation ----------------
__global__ __launch_bounds__(256) void k_alloc(const int* __restrict__ cnt,
                                               int* __restrict__ start,
                                               int* __restrict__ cursor,
                                               int* __restrict__ gcur) {
  __shared__ int wsum[4];
  __shared__ int blockBase;
  int t = threadIdx.x;
  int idx0 = blockIdx.x * 1024 + t * 4;
  int4 cv = *(const int4*)(cnt + idx0);
  int c0 = cv.x, c1 = cv.y, c2 = cv.z, c3 = cv.w;
  int tsum = c0 + c1 + c2 + c3;
  int lane = t & 63, wid = t >> 6;
  int incl = tsum;
#pragma unroll
  for (int off = 1; off < 64; off <<= 1) {
    int v = __shfl_up(incl, off);
    if (lane >= off) incl += v;
  }
  if (lane == 63) wsum[wid] = incl;
  __syncthreads();
  if (t == 0) blockBase = atomicAdd(gcur, wsum[0] + wsum[1] + wsum[2] + wsum[3]);
  __syncthreads();
  int base = blockBase;
  for (int w = 0; w < wid; w++) base += wsum[w];
  int st = base + incl - tsum;
  start[idx0 + 0] = st; cursor[idx0 + 0] = st; st += c0;
  start[idx0 + 1] = st; cursor[idx0 + 1] = st; st += c1;
  start[idx0 + 2] = st; cursor[idx0 + 2] = st; st += c2;
  start[idx0 + 3] = st; cursor[idx0 + 3] = st;
}

// ---------------- counting-sort scatter ----------------
__global__ __launch_bounds__(256) void k_scatter(const int* __restrict__ coords,
                                                 int* __restrict__ cursor,
                                                 int* __restrict__ sorted) {
  int i = blockIdx.x * 256 + threadIdx.x;
  if (i >= PNUM) return;
  int4 c = *(const int4*)(coords + i*4);
  int slot = atomicAdd(&cursor[voxkey(c.x, c.y, c.z, c.w)], 1);
  sorted[slot] = i;
}

// ---------------- active-parent / active-key compaction + m1 + n1 ----------------
__global__ __launch_bounds__(256) void k_plist(const int* __restrict__ cnt,
                                               float* __restrict__ m1,
                                               float* __restrict__ n1f,
                                               int* __restrict__ plist,
                                               int* __restrict__ aklist,
                                               int* __restrict__ nactp,
                                               int* __restrict__ nactk) {
  int p = blockIdx.x * 256 + threadIdx.x;
  int lane = threadIdx.x & 63;
  const int4* c4 = (const int4*)(cnt + (size_t)p*8);
  int4 a = c4[0], b = c4[1];
  int cn[8] = {a.x, a.y, a.z, a.w, b.x, b.y, b.z, b.w};
  int ck = 0;
#pragma unroll
  for (int i = 0; i < 8; i++) ck += (cn[i] > 0) ? 1 : 0;
  bool pa = ck > 0;
  m1[p] = pa ? 1.f : 0.f;
  unsigned long long bal = __ballot(pa);
  int pcnt = __popcll(bal);
  int pbase = 0;
  if (lane == 0) pbase = atomicAdd(nactp, pcnt);
  pbase = __shfl(pbase, 0);
  if (pa) plist[pbase + __popcll(bal & ((1ull << lane) - 1ull))] = p;
  int incl = ck;
#pragma unroll
  for (int o = 1; o < 64; o <<= 1) {
    int v = __shfl_up(incl, o);
    if (lane >= o) incl += v;
  }
  int tot = __shfl(incl, 63);
  int kbase = 0;
  if (lane == 0) kbase = atomicAdd(nactk, tot);
  kbase = __shfl(kbase, 0);
  int off = kbase + incl - ck;
#pragma unroll
  for (int i = 0; i < 8; i++)
    if (cn[i] > 0) aklist[off++] = p*8 + i;
  if (lane == 0) atomicAdd(n1f, (float)pcnt);
}

// ---------------- duplicate-averaging -> bf16 afeat (8 threads/key) ----------------
__global__ __launch_bounds__(256) void k_avg(const float* __restrict__ feat,
                                             const int* __restrict__ sorted,
                                             const int* __restrict__ cnt,
                                             const int* __restrict__ start,
                                             const int* __restrict__ aklist,
                                             const int* __restrict__ nactk,
                                             ushort_t* __restrict__ afb) {
  int gid = blockIdx.x * 256 + threadIdx.x;
  int j = gid >> 3;
  if (j >= nactk[0]) return;
  int key = aklist[j];
  int c = cnt[key];
  int s0 = start[key];
  int q = (gid & 7) * 4;
  float4 acc = {0.f, 0.f, 0.f, 0.f};
  for (int i = 0; i < c; i++) {
    float4 v = *(const float4*)(feat + (size_t)sorted[s0 + i] * 32 + q);
    acc.x += v.x; acc.y += v.y; acc.z += v.z; acc.w += v.w;
  }
  float inv = 1.f / (float)c;
  uint2 o;
  o.x = (uint_t)f2b(acc.x*inv) | ((uint_t)f2b(acc.y*inv) << 16);
  o.y = (uint_t)f2b(acc.z*inv) | ((uint_t)f2b(acc.w*inv) << 16);
  *(uint2*)(afb + (size_t)s0 * 32 + q) = o;
}

// ---------------- weight prep: bf16 + [chunk32][cout][32] layout ----------------
__global__ __launch_bounds__(256) void k_prepw(const float* __restrict__ w1,
                                               const float* __restrict__ w2,
                                               const float* __restrict__ w3,
                                               ushort_t* __restrict__ wt1,
                                               ushort_t* __restrict__ wt2,
                                               ushort_t* __restrict__ wt3) {
  int idx = blockIdx.x * 256 + threadIdx.x;
  if (idx < 16384) {                       // wt1: K=256 (ch*32+ci), CO=64
    int c = idx >> 11, r = idx & 2047;
    int co = r >> 5, kk = r & 31;
    wt1[idx] = f2b(w1[(c*32 + kk)*64 + co]);
  } else if (idx < 16384 + 65536) {        // wt2: K=512 (ch*64+ci), CO=96 pad 128
    int i = idx - 16384;
    int c = i >> 12, r = i & 4095;
    int co = r >> 5, kk = r & 31;
    int k = c*32 + kk;
    wt2[i] = (co < 96) ? f2b(w2[k*96 + co]) : 0;
  } else if (idx < 16384 + 65536 + 131072) { // wt3: K=1024 (ch*128+ci, ci<96 real), CO=128
    int i = idx - 81920;
    int c = i >> 12, r = i & 4095;
    int co = r >> 5, kk = r & 31;
    int k = c*32 + kk;
    int ch = k >> 7, ci = k & 127;
    wt3[i] = (ci < 96) ? f2b(w3[(ch*96 + ci)*128 + co]) : 0;
  }
}

// ---------------- MFMA conv1: 128 active parents x 64 couts ----------------
__global__ __launch_bounds__(256) void k_conv1m(
    const ushort_t* __restrict__ afb, const int* __restrict__ cnt,
    const int* __restrict__ start, const int* __restrict__ plist,
    const int* __restrict__ nactp, const ushort_t* __restrict__ wtg,
    ushort_t* __restrict__ x1b, float* __restrict__ sumv, float* __restrict__ sqv) {
  int nact = nactp[0];
  if (blockIdx.x * 128 >= nact) return;
  __shared__ ushort_t xs[128*40];
  __shared__ ushort_t wt[64*40];
  __shared__ int pl[128];
  __shared__ int cst[128*8];
  int t = threadIdx.x;
#pragma unroll
  for (int ii = 0; ii < 4; ii++) {
    int idx = t + ii*256;
    int s = idx >> 3, ch = idx & 7;
    int gsite = blockIdx.x * 128 + s;
    bool valid = gsite < nact;
    int p = valid ? plist[gsite] : 0;
    if (ch == 0) pl[s] = p;
    int key = p*8 + ch;
    int c = valid ? cnt[key] : 0;
    cst[idx] = (c > 0) ? start[key] : -1;
  }
  int lane = t & 63, wv = t >> 6;
  int l15 = lane & 15, q = lane >> 4;
  int SB = wv * 32;
  v4f acc[2][4];
#pragma unroll
  for (int i = 0; i < 2; i++)
#pragma unroll
    for (int j = 0; j < 4; j++) acc[i][j] = (v4f){0.f, 0.f, 0.f, 0.f};
  for (int c = 0; c < 8; c++) {
    __syncthreads();
    {
      int site = t & 127, part = t >> 7;
      int sp = cst[site*8 + c];
      uint4 u0 = {0,0,0,0}, u1 = {0,0,0,0};
      if (sp >= 0) {
        const uint4* src = (const uint4*)(afb + (size_t)sp*32 + part*16);
        u0 = src[0]; u1 = src[1];
      }
      *(uint4*)&xs[site*40 + part*16]     = u0;
      *(uint4*)&xs[site*40 + part*16 + 8] = u1;
    }
    {
      uint4 w = *(const uint4*)(wtg + c*2048 + t*8);
      *(uint4*)&wt[(t >> 2)*40 + (t & 3)*8] = w;
    }
    __syncthreads();
    v8s a[2], b[4];
#pragma unroll
    for (int mt = 0; mt < 2; mt++)
      a[mt] = *(const v8s*)&xs[(SB + mt*16 + l15)*40 + q*8];
#pragma unroll
    for (int nt = 0; nt < 4; nt++)
      b[nt] = *(const v8s*)&wt[(nt*16 + l15)*40 + q*8];
#pragma unroll
    for (int mt = 0; mt < 2; mt++)
#pragma unroll
      for (int nt = 0; nt < 4; nt++)
        acc[mt][nt] = __builtin_amdgcn_mfma_f32_16x16x32_bf16(a[mt], b[nt], acc[mt][nt], 0, 0, 0);
  }
  float ss[4] = {0,0,0,0}, sq[4] = {0,0,0,0};
#pragma unroll
  for (int mt = 0; mt < 2; mt++) {
#pragma unroll
    for (int nt = 0; nt < 4; nt++) {
#pragma unroll
      for (int r = 0; r < 4; r++) {
        int sl = SB + mt*16 + q*4 + r;
        int gsite = blockIdx.x * 128 + sl;
        ushort_t h = f2b(acc[mt][nt][r]);
        float v = b2f(h);
        if (gsite < nact) x1b[(size_t)pl[sl]*64 + nt*16 + l15] = h;
        ss[nt] += v; sq[nt] += v*v;
      }
    }
  }
#pragma unroll
  for (int nt = 0; nt < 4; nt++) {
    float v1 = ss[nt], v2 = sq[nt];
    v1 += __shfl_xor(v1, 16); v1 += __shfl_xor(v1, 32);
    v2 += __shfl_xor(v2, 16); v2 += __shfl_xor(v2, 32);
    if (lane < 16) {
      atomicAdd(&sumv[nt*16 + l15], v1);
      atomicAdd(&sqv[nt*16 + l15], v2);
    }
  }
}

// ---------------- MFMA conv (conv2/conv3): 128 sites x 128 couts, fused BN in, stats out ----------------
template <int CSTRIDE, int CIN_REAL, int DO, int HO, int WO, int DP, int HP, int WP>
__global__ __launch_bounds__(256) void k_convm(
    const ushort_t* __restrict__ xin, const float* __restrict__ mprev,
    const ushort_t* __restrict__ wtg,
    const float* __restrict__ gam, const float* __restrict__ bet,
    const float* __restrict__ ssumv, const float* __restrict__ ssqv,
    const float* __restrict__ ncnt,
    ushort_t* __restrict__ xout, float* __restrict__ osum, float* __restrict__ osq) {
  const int NCHUNK = CSTRIDE / 4;          // 8*CSTRIDE / 32
  __shared__ ushort_t xs[128*40];
  __shared__ ushort_t wt[128*40];
  __shared__ float sc[CSTRIDE], sh[CSTRIDE];
  __shared__ int   cbase[128*8];
  __shared__ float cmask[128*8];
  int t = threadIdx.x;
  if (t < CSTRIDE) {
    float scv = 0.f, shv = 0.f;
    if (t < CIN_REAL) {
      float n = fmaxf(ncnt[0], 1.0f);
      float mean = ssumv[t] / n;
      float var = ssqv[t] / n - mean * mean;
      float s = gam[t] * rsqrtf(var + EPS_);
      scv = s; shv = bet[t] - mean * s;
    }
    sc[t] = scv; sh[t] = shv;
  }
#pragma unroll
  for (int ii = 0; ii < 4; ii++) {
    int idx = t + ii*256;
    int s = idx >> 3, ch = idx & 7;
    int g = blockIdx.x * 128 + s;
    int b = g / (DO*HO*WO); int r = g - b*(DO*HO*WO);
    int ox = r / (HO*WO); r -= ox*(HO*WO);
    int oy = r / WO; int oz = r - oy*WO;
    int ps = ((b*DP + 2*ox + ((ch >> 2) & 1))*HP + 2*oy + ((ch >> 1) & 1))*WP + 2*oz + (ch & 1);
    cbase[idx] = ps * CSTRIDE;
    cmask[idx] = mprev[ps];
  }
  int lane = t & 63, wv = t >> 6;
  int l15 = lane & 15, q = lane >> 4;
  int SB = (wv & 1) * 64, NB = (wv >> 1) * 64;
  v4f acc[4][4];
#pragma unroll
  for (int i = 0; i < 4; i++)
#pragma unroll
    for (int j = 0; j < 4; j++) acc[i][j] = (v4f){0.f, 0.f, 0.f, 0.f};
  for (int c = 0; c < NCHUNK; c++) {
    __syncthreads();
    {
      int site = t & 127, part = t >> 7;
      int k0 = c * 32;
      int ch = k0 / CSTRIDE;
      int cio = (k0 % CSTRIDE) + part*16;
      const uint_t* src = (const uint_t*)(xin + (size_t)cbase[site*8 + ch] + cio);
      float msk = cmask[site*8 + ch];
      uint_t out[8];
#pragma unroll
      for (int u = 0; u < 8; u++) {
        uint_t w = src[u];
        int ci = cio + u*2;
        float v0 = b2f((ushort_t)(w & 0xffff));
        float v1 = b2f((ushort_t)(w >> 16));
        v0 = v0 * sc[ci] + sh[ci];     v1 = v1 * sc[ci+1] + sh[ci+1];
        v0 = (v0 > 0.f ? v0 : LEAK_*v0) * msk;
        v1 = (v1 > 0.f ? v1 : LEAK_*v1) * msk;
        out[u] = (uint_t)f2b(v0) | ((uint_t)f2b(v1) << 16);
      }
      uint4* dst = (uint4*)&xs[site*40 + part*16];
      dst[0] = make_uint4(out[0], out[1], out[2], out[3]);
      dst[1] = make_uint4(out[4], out[5], out[6], out[7]);
    }
    {
      const uint4* src = (const uint4*)(wtg + (size_t)c*4096 + t*16);
      uint4 w0 = src[0], w1 = src[1];
      uint4* dst = (uint4*)&wt[(t >> 1)*40 + (t & 1)*16];
      dst[0] = w0; dst[1] = w1;
    }
    __syncthreads();
    v8s a[4], b[4];
#pragma unroll
    for (int mt = 0; mt < 4; mt++)
      a[mt] = *(const v8s*)&xs[(SB + mt*16 + l15)*40 + q*8];
#pragma unroll
    for (int nt = 0; nt < 4; nt++)
      b[nt] = *(const v8s*)&wt[(NB + nt*16 + l15)*40 + q*8];
#pragma unroll
    for (int mt = 0; mt < 4; mt++)
#pragma unroll
      for (int nt = 0; nt < 4; nt++)
        acc[mt][nt] = __builtin_amdgcn_mfma_f32_16x16x32_bf16(a[mt], b[nt], acc[mt][nt], 0, 0, 0);
  }
  float ss[4] = {0,0,0,0}, sq[4] = {0,0,0,0};
#pragma unroll
  for (int mt = 0; mt < 4; mt++) {
#pragma unroll
    for (int nt = 0; nt < 4; nt++) {
#pragma unroll
      for (int r = 0; r < 4; r++) {
        int sl = SB + mt*16 + q*4 + r;
        size_t gsite = (size_t)blockIdx.x * 128 + sl;
        ushort_t h = f2b(acc[mt][nt][r]);
        float v = b2f(h);
        xout[gsite*128 + NB + nt*16 + l15] = h;
        ss[nt] += v; sq[nt] += v*v;
      }
    }
  }
#pragma unroll
  for (int nt = 0; nt < 4; nt++) {
    float v1 = ss[nt], v2 = sq[nt];
    v1 += __shfl_xor(v1, 16); v1 += __shfl_xor(v1, 32);
    v2 += __shfl_xor(v2, 16); v2 += __shfl_xor(v2, 32);
    if (lane < 16) {
      atomicAdd(&osum[NB + nt*16 + l15], v1);
      atomicAdd(&osq[NB + nt*16 + l15], v2);
    }
  }
}

// ---------------- mask downsample (+ active count) ----------------
template <int DO, int HO, int WO, int DP, int HP, int WP>
__global__ __launch_bounds__(256) void k_mask(const float* __restrict__ prev,
                                              float* __restrict__ mout,
                                              float* __restrict__ nout, int nsites) {
  int s = blockIdx.x * 256 + threadIdx.x;
  bool act = false;
  if (s < nsites) {
    int b = s / (DO*HO*WO); int r = s - b*(DO*HO*WO);
    int ox = r / (HO*WO); r -= ox*(HO*WO);
    int oy = r / WO; int oz = r - oy*WO;
    int base = ((b*DP + 2*ox)*HP + 2*oy)*WP + 2*oz;
#pragma unroll
    for (int ch = 0; ch < 8; ch++) {
      int idx = base + ((ch >> 2) & 1)*HP*WP + ((ch >> 1) & 1)*WP + (ch & 1);
      act |= (prev[idx] > 0.0f);
    }
    mout[s] = act ? 1.0f : 0.0f;
  }
  unsigned long long bal = __ballot(act);
  if ((threadIdx.x & 63) == 0) atomicAdd(nout, (float)__popcll(bal));
}

// ---------------- final conv (cout=1) + sigmoid + mask ----------------
__global__ __launch_bounds__(256) void k_final(
    const ushort_t* __restrict__ x3b, const float* __restrict__ m3,
    const float* __restrict__ w4, const float* __restrict__ gam,
    const float* __restrict__ bet, const float* __restrict__ ssumv,
    const float* __restrict__ ssqv, const float* __restrict__ ncnt,
    float* __restrict__ out) {
  __shared__ float sc[128], sh[128];
  __shared__ int cb[8];
  __shared__ float msk[8];
  __shared__ float red[256];
  int t = threadIdx.x;
  if (t < 128) {
    float n = fmaxf(ncnt[0], 1.0f);
    float mean = ssumv[t] / n;
    float var = ssqv[t] / n - mean * mean;
    float s = gam[t] * rsqrtf(var + EPS_);
    sc[t] = s; sh[t] = bet[t] - mean * s;
  }
  int g = blockIdx.x;
  int b = g / (D4*H4*W4); int r = g - b*(D4*H4*W4);
  int ox = r / (H4*W4); r -= ox*(H4*W4);
  int oy = r / W4; int oz = r - oy*W4;
  if (t < 8) {
    int ps = ((b*D3 + 2*ox + ((t >> 2) & 1))*H3 + 2*oy + ((t >> 1) & 1))*W3 + 2*oz + (t & 1);
    cb[t] = ps * 128;
    msk[t] = m3[ps];
  }
  __syncthreads();
  float acc = 0.f;
#pragma unroll
  for (int ii = 0; ii < 4; ii++) {
    int k = t + ii*256;
    int ch = k >> 7, ci = k & 127;
    float v = b2f(x3b[cb[ch] + ci]);
    v = v * sc[ci] + sh[ci];
    v = (v > 0.f ? v : LEAK_ * v) * msk[ch];
    acc += v * w4[k];
  }
  red[t] = acc;
  __syncthreads();
  if (t < 128) red[t] += red[t + 128];
  __syncthreads();
  if (t < 64) {
    float v = red[t] + red[t + 64];
#pragma unroll
    for (int off = 32; off > 0; off >>= 1) v += __shfl_down(v, off);
    if (t == 0) {
      float any = (msk[0] + msk[1] + msk[2] + msk[3] + msk[4] + msk[5] + msk[6] + msk[7]) > 0.f ? 1.f : 0.f;
      out[g] = any / (1.0f + expf(-v));
    }
  }
}

extern "C" void kernel_launch(void* const* d_in, const int* in_sizes, int n_in,
                              void* d_out, int out_size, void* d_ws, size_t ws_size,
                              hipStream_t stream) {
  (void)in_sizes; (void)n_in; (void)out_size; (void)ws_size;
  const float* feat = (const float*)d_in[0];
  const int*   crd  = (const int*)d_in[1];
  const float* w1 = (const float*)d_in[2];
  const float* g1 = (const float*)d_in[3];
  const float* b1 = (const float*)d_in[4];
  const float* w2 = (const float*)d_in[5];
  const float* g2 = (const float*)d_in[6];
  const float* b2 = (const float*)d_in[7];
  const float* w3 = (const float*)d_in[8];
  const float* g3 = (const float*)d_in[9];
  const float* b3 = (const float*)d_in[10];
  const float* w4 = (const float*)d_in[11];
  float* out = (float*)d_out;
  float* ws  = (float*)d_ws;

  int*      cnt    = (int*)(ws + OFF_CNT);
  float*    st     = ws + OFF_STATS;
  int*      start  = (int*)(ws + OFF_START);
  int*      sorted = (int*)(ws + OFF_SORTED);
  int*      aklist = (int*)(ws + OFF_AKLIST);
  int*      plist  = (int*)(ws + OFF_PLIST);
  ushort_t* wt1g   = (ushort_t*)(ws + OFF_WT1);
  ushort_t* wt2g   = (ushort_t*)(ws + OFF_WT2);
  ushort_t* wt3g   = (ushort_t*)(ws + OFF_WT3);
  ushort_t* afb    = (ushort_t*)(ws + OFF_AFEATB);
  ushort_t* x1b    = (ushort_t*)(ws + OFF_X1B);
  int*      cursor = (int*)(ws + OFF_X1B);   // overlays x1b head; dead after k_scatter
  ushort_t* x2b    = (ushort_t*)(ws + OFF_X2B);
  ushort_t* x3b    = (ushort_t*)(ws + OFF_X3B);
  float*    m1     = ws + OFF_M1;
  float*    m2     = ws + OFF_M2;
  float*    m3     = ws + OFF_M3;

  hipMemsetAsync(d_ws, 0, (size_t)(OFF_STATS + 1024) * sizeof(float), stream);

  k_count<<<(PNUM + 255) / 256, 256, 0, stream>>>(crd, cnt);
  k_alloc<<<NVOX / 1024, 256, 0, stream>>>(cnt, start, cursor, (int*)(st + 643));
  k_scatter<<<(PNUM + 255) / 256, 256, 0, stream>>>(crd, cursor, sorted);
  k_plist<<<N1S / 256, 256, 0, stream>>>(cnt, m1, st + 640, plist, aklist,
                                         (int*)(st + 644), (int*)(st + 645));
  k_avg<<<(PNUM * 8) / 256 + 1, 256, 0, stream>>>(feat, sorted, cnt, start, aklist,
                                                  (const int*)(st + 645), afb);
  k_prepw<<<(16384 + 65536 + 131072) / 256, 256, 0, stream>>>(w1, w2, w3, wt1g, wt2g, wt3g);
  hipMemsetAsync(x1b, 0, (size_t)N1S * 64 * sizeof(ushort_t), stream);
  k_conv1m<<<(N1S + 127) / 128, 256, 0, stream>>>(afb, cnt, start, plist,
                                                  (const int*)(st + 644), wt1g,
                                                  x1b, st + 0, st + 64);
  k_mask<D2,H2,W2, D1,H1,W1><<<N2S / 256, 256, 0, stream>>>(m1, m2, st + 641, N2S);
  k_convm<64, 64, D2,H2,W2, D1,H1,W1><<<N2S / 128, 256, 0, stream>>>(
      x1b, m1, wt2g, g1, b1, st + 0, st + 64, st + 640, x2b, st + 128, st + 256);
  k_mask<D3,H3,W3, D2,H2,W2><<<(N3S + 255) / 256, 256, 0, stream>>>(m2, m3, st + 642, N3S);
  k_convm<128, 96, D3,H3,W3, D2,H2,W2><<<N3S / 128, 256, 0, stream>>>(
      x2b, m2, wt3g, g2, b2, st + 128, st + 256, st + 641, x3b, st + 384, st + 512);
  k_final<<<N4S, 256, 0, stream>>>(x3b, m3, w4, g3, b3, st + 384, st + 512, st + 642, out);
}

// Round 6
// 542.514 us; speedup vs baseline: 2.1492x; 1.2293x over previous
//
#include <hip/hip_runtime.h>
#include <math.h>

#define PNUM 300000
#define B_ 2
#define D0 144
#define H0 64
#define W0 160
#define NVOX (B_*D0*H0*W0)   // 2,949,120

#define D1 72
#define H1 32
#define W1 80
#define N1S (B_*D1*H1*W1)   // 368640

#define D2 36
#define H2 16
#define W2 40
#define N2S (B_*D2*H2*W2)   // 46080

#define D3 18
#define H3 8
#define W3 20
#define N3S (B_*D3*H3*W3)   // 5760

#define D4 9
#define H4 4
#define W4 10
#define N4S (B_*D4*H4*W4)   // 720

#define EPS_ 1e-4f
#define LEAK_ 0.2f

typedef __attribute__((ext_vector_type(8))) short v8s;   // 8 bf16 (4 VGPRs)
typedef __attribute__((ext_vector_type(4))) float v4f;

typedef unsigned short ushort_t;
typedef unsigned int uint_t;

__device__ __forceinline__ ushort_t f2b(float f) {
  union { float f; uint_t u; } x; x.f = f;
  uint_t r = x.u + 0x7FFFu + ((x.u >> 16) & 1u);   // RNE
  return (ushort_t)(r >> 16);
}
__device__ __forceinline__ float b2f(ushort_t h) {
  union { uint_t u; float f; } x; x.u = ((uint_t)h) << 16; return x.f;
}

// workspace layout (4-byte word offsets) -- ~109 MB
#define OFF_CNT     0
#define OFF_STATS   2949120
#define OFF_START   2950144
#define OFF_SORTED  5899264
#define OFF_AKLIST  6199264
#define OFF_PLIST   6499264
#define OFF_WT1     6867904
#define OFF_WT2     6876096
#define OFF_WT3     6908864
#define OFF_AFEATB  6974400
#define OFF_X1B     11774400
#define OFF_X2B     23570880
#define OFF_X3B     26520000
#define OFF_M1      26888640
#define OFF_M2      27257280
#define OFF_M3      27303360

__device__ __forceinline__ int voxkey(int b, int x, int y, int z) {
  int p = ((b*D1 + (x >> 1))*H1 + (y >> 1))*W1 + (z >> 1);
  int oct = ((x & 1) << 2) | ((y & 1) << 1) | (z & 1);
  return p*8 + oct;
}

// ---------------- densify count ----------------
__global__ __launch_bounds__(256) void k_count(const int* __restrict__ coords,
                                               int* __restrict__ cnt) {
  int i = blockIdx.x * 256 + threadIdx.x;
  if (i >= PNUM) return;
  int4 c = *(const int4*)(coords + i*4);
  atomicAdd(&cnt[voxkey(c.x, c.y, c.z, c.w)], 1);
}

// ---------------- slot allocation ----------------
__global__ __launch_bounds__(256) void k_alloc(const int* __restrict__ cnt,
                                               int* __restrict__ start,
                                               int* __restrict__ cursor,
                                               int* __restrict__ gcur) {
  __shared__ int wsum[4];
  __shared__ int blockBase;
  int t = threadIdx.x;
  int idx0 = blockIdx.x * 1024 + t * 4;
  int4 cv = *(const int4*)(cnt + idx0);
  int c0 = cv.x, c1 = cv.y, c2 = cv.z, c3 = cv.w;
  int tsum = c0 + c1 + c2 + c3;
  int lane = t & 63, wid = t >> 6;
  int incl = tsum;
#pragma unroll
  for (int off = 1; off < 64; off <<= 1) {
    int v = __shfl_up(incl, off);
    if (lane >= off) incl += v;
  }
  if (lane == 63) wsum[wid] = incl;
  __syncthreads();
  if (t == 0) blockBase = atomicAdd(gcur, wsum[0] + wsum[1] + wsum[2] + wsum[3]);
  __syncthreads();
  int base = blockBase;
  for (int w = 0; w < wid; w++) base += wsum[w];
  int st = base + incl - tsum;
  start[idx0 + 0] = st; cursor[idx0 + 0] = st; st += c0;
  start[idx0 + 1] = st; cursor[idx0 + 1] = st; st += c1;
  start[idx0 + 2] = st; cursor[idx0 + 2] = st; st += c2;
  start[idx0 + 3] = st; cursor[idx0 + 3] = st;
}

// ---------------- counting-sort scatter ----------------
__global__ __launch_bounds__(256) void k_scatter(const int* __restrict__ coords,
                                                 int* __restrict__ cursor,
                                                 int* __restrict__ sorted) {
  int i = blockIdx.x * 256 + threadIdx.x;
  if (i >= PNUM) return;
  int4 c = *(const int4*)(coords + i*4);
  int slot = atomicAdd(&cursor[voxkey(c.x, c.y, c.z, c.w)], 1);
  sorted[slot] = i;
}

// ---------------- active-parent / active-key compaction + m1 + n1 ----------------
__global__ __launch_bounds__(256) void k_plist(const int* __restrict__ cnt,
                                               float* __restrict__ m1,
                                               float* __restrict__ n1f,
                                               int* __restrict__ plist,
                                               int* __restrict__ aklist,
                                               int* __restrict__ nactp,
                                               int* __restrict__ nactk) {
  int p = blockIdx.x * 256 + threadIdx.x;
  int lane = threadIdx.x & 63;
  const int4* c4 = (const int4*)(cnt + (size_t)p*8);
  int4 a = c4[0], b = c4[1];
  int cn[8] = {a.x, a.y, a.z, a.w, b.x, b.y, b.z, b.w};
  int ck = 0;
#pragma unroll
  for (int i = 0; i < 8; i++) ck += (cn[i] > 0) ? 1 : 0;
  bool pa = ck > 0;
  m1[p] = pa ? 1.f : 0.f;
  unsigned long long bal = __ballot(pa);
  int pcnt = __popcll(bal);
  int pbase = 0;
  if (lane == 0) pbase = atomicAdd(nactp, pcnt);
  pbase = __shfl(pbase, 0);
  if (pa) plist[pbase + __popcll(bal & ((1ull << lane) - 1ull))] = p;
  int incl = ck;
#pragma unroll
  for (int o = 1; o < 64; o <<= 1) {
    int v = __shfl_up(incl, o);
    if (lane >= o) incl += v;
  }
  int tot = __shfl(incl, 63);
  int kbase = 0;
  if (lane == 0) kbase = atomicAdd(nactk, tot);
  kbase = __shfl(kbase, 0);
  int off = kbase + incl - ck;
#pragma unroll
  for (int i = 0; i < 8; i++)
    if (cn[i] > 0) aklist[off++] = p*8 + i;
  if (lane == 0) atomicAdd(n1f, (float)pcnt);
}

// ---------------- duplicate-averaging -> bf16 afeat (8 threads/key) ----------------
__global__ __launch_bounds__(256) void k_avg(const float* __restrict__ feat,
                                             const int* __restrict__ sorted,
                                             const int* __restrict__ cnt,
                                             const int* __restrict__ start,
                                             const int* __restrict__ aklist,
                                             const int* __restrict__ nactk,
                                             ushort_t* __restrict__ afb) {
  int gid = blockIdx.x * 256 + threadIdx.x;
  int j = gid >> 3;
  if (j >= nactk[0]) return;
  int key = aklist[j];
  int c = cnt[key];
  int s0 = start[key];
  int q = (gid & 7) * 4;
  float4 acc = {0.f, 0.f, 0.f, 0.f};
  for (int i = 0; i < c; i++) {
    float4 v = *(const float4*)(feat + (size_t)sorted[s0 + i] * 32 + q);
    acc.x += v.x; acc.y += v.y; acc.z += v.z; acc.w += v.w;
  }
  float inv = 1.f / (float)c;
  uint2 o;
  o.x = (uint_t)f2b(acc.x*inv) | ((uint_t)f2b(acc.y*inv) << 16);
  o.y = (uint_t)f2b(acc.z*inv) | ((uint_t)f2b(acc.w*inv) << 16);
  *(uint2*)(afb + (size_t)s0 * 32 + q) = o;
}

// ---------------- weight prep: bf16 + [chunk32][cout][32] layout ----------------
__global__ __launch_bounds__(256) void k_prepw(const float* __restrict__ w1,
                                               const float* __restrict__ w2,
                                               const float* __restrict__ w3,
                                               ushort_t* __restrict__ wt1,
                                               ushort_t* __restrict__ wt2,
                                               ushort_t* __restrict__ wt3) {
  int idx = blockIdx.x * 256 + threadIdx.x;
  if (idx < 16384) {                       // wt1: K=256 (ch*32+ci), CO=64
    int c = idx >> 11, r = idx & 2047;
    int co = r >> 5, kk = r & 31;
    wt1[idx] = f2b(w1[(c*32 + kk)*64 + co]);
  } else if (idx < 16384 + 65536) {        // wt2: K=512 (ch*64+ci), CO=96 pad 128
    int i = idx - 16384;
    int c = i >> 12, r = i & 4095;
    int co = r >> 5, kk = r & 31;
    int k = c*32 + kk;
    wt2[i] = (co < 96) ? f2b(w2[k*96 + co]) : 0;
  } else if (idx < 16384 + 65536 + 131072) { // wt3: K=1024 (ch*128+ci, ci<96 real), CO=128
    int i = idx - 81920;
    int c = i >> 12, r = i & 4095;
    int co = r >> 5, kk = r & 31;
    int k = c*32 + kk;
    int ch = k >> 7, ci = k & 127;
    wt3[i] = (ci < 96) ? f2b(w3[(ch*96 + ci)*128 + co]) : 0;
  }
}

// ---------------- MFMA conv1: 128 active parents x 64 couts ----------------
// stats: wave-shuffle reduce -> LDS cross-wave reduce -> 1 atomic/channel/block
__global__ __launch_bounds__(256) void k_conv1m(
    const ushort_t* __restrict__ afb, const int* __restrict__ cnt,
    const int* __restrict__ start, const int* __restrict__ plist,
    const int* __restrict__ nactp, const ushort_t* __restrict__ wtg,
    ushort_t* __restrict__ x1b, float* __restrict__ sumv, float* __restrict__ sqv) {
  int nact = nactp[0];
  if (blockIdx.x * 128 >= nact) return;
  __shared__ ushort_t xs[128*40];
  __shared__ ushort_t wt[64*40];
  __shared__ int pl[128];
  __shared__ int cst[128*8];
  __shared__ float redS[4][64], redQ[4][64];
  int t = threadIdx.x;
#pragma unroll
  for (int ii = 0; ii < 4; ii++) {
    int idx = t + ii*256;
    int s = idx >> 3, ch = idx & 7;
    int gsite = blockIdx.x * 128 + s;
    bool valid = gsite < nact;
    int p = valid ? plist[gsite] : 0;
    if (ch == 0) pl[s] = p;
    int key = p*8 + ch;
    int c = valid ? cnt[key] : 0;
    cst[idx] = (c > 0) ? start[key] : -1;
  }
  int lane = t & 63, wv = t >> 6;
  int l15 = lane & 15, q = lane >> 4;
  int SB = wv * 32;
  v4f acc[2][4];
#pragma unroll
  for (int i = 0; i < 2; i++)
#pragma unroll
    for (int j = 0; j < 4; j++) acc[i][j] = (v4f){0.f, 0.f, 0.f, 0.f};
  for (int c = 0; c < 8; c++) {
    __syncthreads();
    {
      int site = t & 127, part = t >> 7;
      int sp = cst[site*8 + c];
      uint4 u0 = {0,0,0,0}, u1 = {0,0,0,0};
      if (sp >= 0) {
        const uint4* src = (const uint4*)(afb + (size_t)sp*32 + part*16);
        u0 = src[0]; u1 = src[1];
      }
      *(uint4*)&xs[site*40 + part*16]     = u0;
      *(uint4*)&xs[site*40 + part*16 + 8] = u1;
    }
    {
      uint4 w = *(const uint4*)(wtg + c*2048 + t*8);
      *(uint4*)&wt[(t >> 2)*40 + (t & 3)*8] = w;
    }
    __syncthreads();
    v8s a[2], b[4];
#pragma unroll
    for (int mt = 0; mt < 2; mt++)
      a[mt] = *(const v8s*)&xs[(SB + mt*16 + l15)*40 + q*8];
#pragma unroll
    for (int nt = 0; nt < 4; nt++)
      b[nt] = *(const v8s*)&wt[(nt*16 + l15)*40 + q*8];
#pragma unroll
    for (int mt = 0; mt < 2; mt++)
#pragma unroll
      for (int nt = 0; nt < 4; nt++)
        acc[mt][nt] = __builtin_amdgcn_mfma_f32_16x16x32_bf16(a[mt], b[nt], acc[mt][nt], 0, 0, 0);
  }
  float ss[4] = {0,0,0,0}, sq[4] = {0,0,0,0};
#pragma unroll
  for (int mt = 0; mt < 2; mt++) {
#pragma unroll
    for (int nt = 0; nt < 4; nt++) {
#pragma unroll
      for (int r = 0; r < 4; r++) {
        int sl = SB + mt*16 + q*4 + r;
        int gsite = blockIdx.x * 128 + sl;
        ushort_t h = f2b(acc[mt][nt][r]);
        float v = b2f(h);
        if (gsite < nact) x1b[(size_t)pl[sl]*64 + nt*16 + l15] = h;
        ss[nt] += v; sq[nt] += v*v;
      }
    }
  }
#pragma unroll
  for (int nt = 0; nt < 4; nt++) {
    float v1 = ss[nt], v2 = sq[nt];
    v1 += __shfl_xor(v1, 16); v1 += __shfl_xor(v1, 32);
    v2 += __shfl_xor(v2, 16); v2 += __shfl_xor(v2, 32);
    if (lane < 16) { redS[wv][nt*16 + l15] = v1; redQ[wv][nt*16 + l15] = v2; }
  }
  __syncthreads();
  if (t < 64) {
    float s = redS[0][t] + redS[1][t] + redS[2][t] + redS[3][t];
    float qq = redQ[0][t] + redQ[1][t] + redQ[2][t] + redQ[3][t];
    atomicAdd(&sumv[t], s);
    atomicAdd(&sqv[t], qq);
  }
}

// ---------------- MFMA conv (conv2/conv3): 128 sites x 128 couts ----------------
template <int CSTRIDE, int CIN_REAL, int DO, int HO, int WO, int DP, int HP, int WP>
__global__ __launch_bounds__(256) void k_convm(
    const ushort_t* __restrict__ xin, const float* __restrict__ mprev,
    const ushort_t* __restrict__ wtg,
    const float* __restrict__ gam, const float* __restrict__ bet,
    const float* __restrict__ ssumv, const float* __restrict__ ssqv,
    const float* __restrict__ ncnt,
    ushort_t* __restrict__ xout, float* __restrict__ osum, float* __restrict__ osq) {
  const int NCHUNK = CSTRIDE / 4;
  __shared__ ushort_t xs[128*40];
  __shared__ ushort_t wt[128*40];
  __shared__ float sc[CSTRIDE], sh[CSTRIDE];
  __shared__ int   cbase[128*8];
  __shared__ float cmask[128*8];
  __shared__ float redS[4][64], redQ[4][64];
  int t = threadIdx.x;
  if (t < CSTRIDE) {
    float scv = 0.f, shv = 0.f;
    if (t < CIN_REAL) {
      float n = fmaxf(ncnt[0], 1.0f);
      float mean = ssumv[t] / n;
      float var = ssqv[t] / n - mean * mean;
      float s = gam[t] * rsqrtf(var + EPS_);
      scv = s; shv = bet[t] - mean * s;
    }
    sc[t] = scv; sh[t] = shv;
  }
#pragma unroll
  for (int ii = 0; ii < 4; ii++) {
    int idx = t + ii*256;
    int s = idx >> 3, ch = idx & 7;
    int g = blockIdx.x * 128 + s;
    int b = g / (DO*HO*WO); int r = g - b*(DO*HO*WO);
    int ox = r / (HO*WO); r -= ox*(HO*WO);
    int oy = r / WO; int oz = r - oy*WO;
    int ps = ((b*DP + 2*ox + ((ch >> 2) & 1))*HP + 2*oy + ((ch >> 1) & 1))*WP + 2*oz + (ch & 1);
    cbase[idx] = ps * CSTRIDE;
    cmask[idx] = mprev[ps];
  }
  int lane = t & 63, wv = t >> 6;
  int l15 = lane & 15, q = lane >> 4;
  int SB = (wv & 1) * 64, NB = (wv >> 1) * 64;
  v4f acc[4][4];
#pragma unroll
  for (int i = 0; i < 4; i++)
#pragma unroll
    for (int j = 0; j < 4; j++) acc[i][j] = (v4f){0.f, 0.f, 0.f, 0.f};
  for (int c = 0; c < NCHUNK; c++) {
    __syncthreads();
    {
      int site = t & 127, part = t >> 7;
      int k0 = c * 32;
      int ch = k0 / CSTRIDE;
      int cio = (k0 % CSTRIDE) + part*16;
      const uint_t* src = (const uint_t*)(xin + (size_t)cbase[site*8 + ch] + cio);
      float msk = cmask[site*8 + ch];
      uint_t out[8];
#pragma unroll
      for (int u = 0; u < 8; u++) {
        uint_t w = src[u];
        int ci = cio + u*2;
        float v0 = b2f((ushort_t)(w & 0xffff));
        float v1 = b2f((ushort_t)(w >> 16));
        v0 = v0 * sc[ci] + sh[ci];     v1 = v1 * sc[ci+1] + sh[ci+1];
        v0 = (v0 > 0.f ? v0 : LEAK_*v0) * msk;
        v1 = (v1 > 0.f ? v1 : LEAK_*v1) * msk;
        out[u] = (uint_t)f2b(v0) | ((uint_t)f2b(v1) << 16);
      }
      uint4* dst = (uint4*)&xs[site*40 + part*16];
      dst[0] = make_uint4(out[0], out[1], out[2], out[3]);
      dst[1] = make_uint4(out[4], out[5], out[6], out[7]);
    }
    {
      const uint4* src = (const uint4*)(wtg + (size_t)c*4096 + t*16);
      uint4 w0 = src[0], w1 = src[1];
      uint4* dst = (uint4*)&wt[(t >> 1)*40 + (t & 1)*16];
      dst[0] = w0; dst[1] = w1;
    }
    __syncthreads();
    v8s a[4], b[4];
#pragma unroll
    for (int mt = 0; mt < 4; mt++)
      a[mt] = *(const v8s*)&xs[(SB + mt*16 + l15)*40 + q*8];
#pragma unroll
    for (int nt = 0; nt < 4; nt++)
      b[nt] = *(const v8s*)&wt[(NB + nt*16 + l15)*40 + q*8];
#pragma unroll
    for (int mt = 0; mt < 4; mt++)
#pragma unroll
      for (int nt = 0; nt < 4; nt++)
        acc[mt][nt] = __builtin_amdgcn_mfma_f32_16x16x32_bf16(a[mt], b[nt], acc[mt][nt], 0, 0, 0);
  }
  float ss[4] = {0,0,0,0}, sq[4] = {0,0,0,0};
#pragma unroll
  for (int mt = 0; mt < 4; mt++) {
#pragma unroll
    for (int nt = 0; nt < 4; nt++) {
#pragma unroll
      for (int r = 0; r < 4; r++) {
        int sl = SB + mt*16 + q*4 + r;
        size_t gsite = (size_t)blockIdx.x * 128 + sl;
        ushort_t h = f2b(acc[mt][nt][r]);
        float v = b2f(h);
        xout[gsite*128 + NB + nt*16 + l15] = h;
        ss[nt] += v; sq[nt] += v*v;
      }
    }
  }
#pragma unroll
  for (int nt = 0; nt < 4; nt++) {
    float v1 = ss[nt], v2 = sq[nt];
    v1 += __shfl_xor(v1, 16); v1 += __shfl_xor(v1, 32);
    v2 += __shfl_xor(v2, 16); v2 += __shfl_xor(v2, 32);
    if (lane < 16) { redS[wv][nt*16 + l15] = v1; redQ[wv][nt*16 + l15] = v2; }
  }
  __syncthreads();
  if (t < 128) {
    float s, qq;
    if (t < 64) { s = redS[0][t] + redS[1][t]; qq = redQ[0][t] + redQ[1][t]; }
    else        { s = redS[2][t-64] + redS[3][t-64]; qq = redQ[2][t-64] + redQ[3][t-64]; }
    atomicAdd(&osum[t], s);
    atomicAdd(&osq[t], qq);
  }
}

// ---------------- mask downsample (+ active count) ----------------
template <int DO, int HO, int WO, int DP, int HP, int WP>
__global__ __launch_bounds__(256) void k_mask(const float* __restrict__ prev,
                                              float* __restrict__ mout,
                                              float* __restrict__ nout, int nsites) {
  int s = blockIdx.x * 256 + threadIdx.x;
  bool act = false;
  if (s < nsites) {
    int b = s / (DO*HO*WO); int r = s - b*(DO*HO*WO);
    int ox = r / (HO*WO); r -= ox*(HO*WO);
    int oy = r / WO; int oz = r - oy*WO;
    int base = ((b*DP + 2*ox)*HP + 2*oy)*WP + 2*oz;
#pragma unroll
    for (int ch = 0; ch < 8; ch++) {
      int idx = base + ((ch >> 2) & 1)*HP*WP + ((ch >> 1) & 1)*WP + (ch & 1);
      act |= (prev[idx] > 0.0f);
    }
    mout[s] = act ? 1.0f : 0.0f;
  }
  unsigned long long bal = __ballot(act);
  if ((threadIdx.x & 63) == 0) atomicAdd(nout, (float)__popcll(bal));
}

// ---------------- final conv (cout=1) + sigmoid + mask ----------------
__global__ __launch_bounds__(256) void k_final(
    const ushort_t* __restrict__ x3b, const float* __restrict__ m3,
    const float* __restrict__ w4, const float* __restrict__ gam,
    const float* __restrict__ bet, const float* __restrict__ ssumv,
    const float* __restrict__ ssqv, const float* __restrict__ ncnt,
    float* __restrict__ out) {
  __shared__ float sc[128], sh[128];
  __shared__ int cb[8];
  __shared__ float msk[8];
  __shared__ float red[256];
  int t = threadIdx.x;
  if (t < 128) {
    float n = fmaxf(ncnt[0], 1.0f);
    float mean = ssumv[t] / n;
    float var = ssqv[t] / n - mean * mean;
    float s = gam[t] * rsqrtf(var + EPS_);
    sc[t] = s; sh[t] = bet[t] - mean * s;
  }
  int g = blockIdx.x;
  int b = g / (D4*H4*W4); int r = g - b*(D4*H4*W4);
  int ox = r / (H4*W4); r -= ox*(H4*W4);
  int oy = r / W4; int oz = r - oy*W4;
  if (t < 8) {
    int ps = ((b*D3 + 2*ox + ((t >> 2) & 1))*H3 + 2*oy + ((t >> 1) & 1))*W3 + 2*oz + (t & 1);
    cb[t] = ps * 128;
    msk[t] = m3[ps];
  }
  __syncthreads();
  float acc = 0.f;
#pragma unroll
  for (int ii = 0; ii < 4; ii++) {
    int k = t + ii*256;
    int ch = k >> 7, ci = k & 127;
    float v = b2f(x3b[cb[ch] + ci]);
    v = v * sc[ci] + sh[ci];
    v = (v > 0.f ? v : LEAK_ * v) * msk[ch];
    acc += v * w4[k];
  }
  red[t] = acc;
  __syncthreads();
  if (t < 128) red[t] += red[t + 128];
  __syncthreads();
  if (t < 64) {
    float v = red[t] + red[t + 64];
#pragma unroll
    for (int off = 32; off > 0; off >>= 1) v += __shfl_down(v, off);
    if (t == 0) {
      float any = (msk[0] + msk[1] + msk[2] + msk[3] + msk[4] + msk[5] + msk[6] + msk[7]) > 0.f ? 1.f : 0.f;
      out[g] = any / (1.0f + expf(-v));
    }
  }
}

extern "C" void kernel_launch(void* const* d_in, const int* in_sizes, int n_in,
                              void* d_out, int out_size, void* d_ws, size_t ws_size,
                              hipStream_t stream) {
  (void)in_sizes; (void)n_in; (void)out_size; (void)ws_size;
  const float* feat = (const float*)d_in[0];
  const int*   crd  = (const int*)d_in[1];
  const float* w1 = (const float*)d_in[2];
  const float* g1 = (const float*)d_in[3];
  const float* b1 = (const float*)d_in[4];
  const float* w2 = (const float*)d_in[5];
  const float* g2 = (const float*)d_in[6];
  const float* b2 = (const float*)d_in[7];
  const float* w3 = (const float*)d_in[8];
  const float* g3 = (const float*)d_in[9];
  const float* b3 = (const float*)d_in[10];
  const float* w4 = (const float*)d_in[11];
  float* out = (float*)d_out;
  float* ws  = (float*)d_ws;

  int*      cnt    = (int*)(ws + OFF_CNT);
  float*    st     = ws + OFF_STATS;
  int*      start  = (int*)(ws + OFF_START);
  int*      sorted = (int*)(ws + OFF_SORTED);
  int*      aklist = (int*)(ws + OFF_AKLIST);
  int*      plist  = (int*)(ws + OFF_PLIST);
  ushort_t* wt1g   = (ushort_t*)(ws + OFF_WT1);
  ushort_t* wt2g   = (ushort_t*)(ws + OFF_WT2);
  ushort_t* wt3g   = (ushort_t*)(ws + OFF_WT3);
  ushort_t* afb    = (ushort_t*)(ws + OFF_AFEATB);
  ushort_t* x1b    = (ushort_t*)(ws + OFF_X1B);
  int*      cursor = (int*)(ws + OFF_X1B);   // overlays x1b head; dead after k_scatter
  ushort_t* x2b    = (ushort_t*)(ws + OFF_X2B);
  ushort_t* x3b    = (ushort_t*)(ws + OFF_X3B);
  float*    m1     = ws + OFF_M1;
  float*    m2     = ws + OFF_M2;
  float*    m3     = ws + OFF_M3;

  hipMemsetAsync(d_ws, 0, (size_t)(OFF_STATS + 1024) * sizeof(float), stream);

  k_count<<<(PNUM + 255) / 256, 256, 0, stream>>>(crd, cnt);
  k_alloc<<<NVOX / 1024, 256, 0, stream>>>(cnt, start, cursor, (int*)(st + 643));
  k_scatter<<<(PNUM + 255) / 256, 256, 0, stream>>>(crd, cursor, sorted);
  k_plist<<<N1S / 256, 256, 0, stream>>>(cnt, m1, st + 640, plist, aklist,
                                         (int*)(st + 644), (int*)(st + 645));
  k_avg<<<(PNUM * 8) / 256 + 1, 256, 0, stream>>>(feat, sorted, cnt, start, aklist,
                                                  (const int*)(st + 645), afb);
  k_prepw<<<(16384 + 65536 + 131072) / 256, 256, 0, stream>>>(w1, w2, w3, wt1g, wt2g, wt3g);
  hipMemsetAsync(x1b, 0, (size_t)N1S * 64 * sizeof(ushort_t), stream);
  k_conv1m<<<(N1S + 127) / 128, 256, 0, stream>>>(afb, cnt, start, plist,
                                                  (const int*)(st + 644), wt1g,
                                                  x1b, st + 0, st + 64);
  k_mask<D2,H2,W2, D1,H1,W1><<<N2S / 256, 256, 0, stream>>>(m1, m2, st + 641, N2S);
  k_convm<64, 64, D2,H2,W2, D1,H1,W1><<<N2S / 128, 256, 0, stream>>>(
      x1b, m1, wt2g, g1, b1, st + 0, st + 64, st + 640, x2b, st + 128, st + 256);
  k_mask<D3,H3,W3, D2,H2,W2><<<(N3S + 255) / 256, 256, 0, stream>>>(m2, m3, st + 642, N3S);
  k_convm<128, 96, D3,H3,W3, D2,H2,W2><<<N3S / 128, 256, 0, stream>>>(
      x2b, m2, wt3g, g2, b2, st + 128, st + 256, st + 641, x3b, st + 384, st + 512);
  k_final<<<N4S, 256, 0, stream>>>(x3b, m3, w4, g3, b3, st + 384, st + 512, st + 642, out);
}

// Round 7
// 316.931 us; speedup vs baseline: 3.6789x; 1.7118x over previous
//
#include <hip/hip_runtime.h>
#include <math.h>

#define PNUM 300000
#define B_ 2
#define D0 144
#define H0 64
#define W0 160
#define NVOX (B_*D0*H0*W0)   // 2,949,120

#define D1 72
#define H1 32
#define W1 80
#define N1S (B_*D1*H1*W1)   // 368640

#define D2 36
#define H2 16
#define W2 40
#define N2S (B_*D2*H2*W2)   // 46080

#define D3 18
#define H3 8
#define W3 20
#define N3S (B_*D3*H3*W3)   // 5760

#define D4 9
#define H4 4
#define W4 10
#define N4S (B_*D4*H4*W4)   // 720

#define EPS_ 1e-4f
#define LEAK_ 0.2f

typedef __attribute__((ext_vector_type(8))) short v8s;   // 8 bf16 (4 VGPRs)
typedef __attribute__((ext_vector_type(4))) float v4f;

typedef unsigned short ushort_t;
typedef unsigned int uint_t;
typedef unsigned long long ull_t;

__device__ __forceinline__ ushort_t f2b(float f) {
  union { float f; uint_t u; } x; x.f = f;
  uint_t r = x.u + 0x7FFFu + ((x.u >> 16) & 1u);   // RNE
  return (ushort_t)(r >> 16);
}
__device__ __forceinline__ float b2f(ushort_t h) {
  union { uint_t u; float f; } x; x.u = ((uint_t)h) << 16; return x.f;
}

// workspace layout (4-byte word offsets) -- ~109 MB
#define OFF_CNT     0
#define OFF_STATS   2949120    // s1@0 q1@64 s2@128 q2@256 s3@384 q3@512 n2@641 n3@642 gcur@643 pk@644(ull: lo=k,hi=p)
#define OFF_START   2950144
#define OFF_SORTED  5899264
#define OFF_AKLIST  6199264
#define OFF_PLIST   6499264
#define OFF_WT1     6867904
#define OFF_WT2     6876096
#define OFF_WT3     6908864
#define OFF_AFEATB  6974400
#define OFF_X1B     11774400
#define OFF_X2B     23570880
#define OFF_X3B     26520000
#define OFF_M1      26888640
#define OFF_M2      27257280
#define OFF_M3      27303360

__device__ __forceinline__ int voxkey(int b, int x, int y, int z) {
  int p = ((b*D1 + (x >> 1))*H1 + (y >> 1))*W1 + (z >> 1);
  int oct = ((x & 1) << 2) | ((y & 1) << 1) | (z & 1);
  return p*8 + oct;
}

// ---------------- densify count ----------------
__global__ __launch_bounds__(256) void k_count(const int* __restrict__ coords,
                                               int* __restrict__ cnt) {
  int i = blockIdx.x * 256 + threadIdx.x;
  if (i >= PNUM) return;
  int4 c = *(const int4*)(coords + i*4);
  atomicAdd(&cnt[voxkey(c.x, c.y, c.z, c.w)], 1);
}

// ---------------- slot allocation: 1024 threads, 4096 voxels, 1 ticket/block ----------------
__global__ __launch_bounds__(1024) void k_alloc(const int* __restrict__ cnt,
                                                int* __restrict__ start,
                                                int* __restrict__ cursor,
                                                int* __restrict__ gcur) {
  __shared__ int wsum[16];
  __shared__ int blockBase;
  int t = threadIdx.x;
  int idx0 = blockIdx.x * 4096 + t * 4;
  int4 cv = *(const int4*)(cnt + idx0);
  int c0 = cv.x, c1 = cv.y, c2 = cv.z, c3 = cv.w;
  int tsum = c0 + c1 + c2 + c3;
  int lane = t & 63, wid = t >> 6;
  int incl = tsum;
#pragma unroll
  for (int off = 1; off < 64; off <<= 1) {
    int v = __shfl_up(incl, off);
    if (lane >= off) incl += v;
  }
  if (lane == 63) wsum[wid] = incl;
  __syncthreads();
  if (t == 0) {
    int tot = 0;
#pragma unroll
    for (int w = 0; w < 16; w++) { int v = wsum[w]; wsum[w] = tot; tot += v; }
    blockBase = atomicAdd(gcur, tot);
  }
  __syncthreads();
  int st = blockBase + wsum[wid] + incl - tsum;
  start[idx0 + 0] = st; cursor[idx0 + 0] = st; st += c0;
  start[idx0 + 1] = st; cursor[idx0 + 1] = st; st += c1;
  start[idx0 + 2] = st; cursor[idx0 + 2] = st; st += c2;
  start[idx0 + 3] = st; cursor[idx0 + 3] = st;
}

// ---------------- counting-sort scatter ----------------
__global__ __launch_bounds__(256) void k_scatter(const int* __restrict__ coords,
                                                 int* __restrict__ cursor,
                                                 int* __restrict__ sorted) {
  int i = blockIdx.x * 256 + threadIdx.x;
  if (i >= PNUM) return;
  int4 c = *(const int4*)(coords + i*4);
  int slot = atomicAdd(&cursor[voxkey(c.x, c.y, c.z, c.w)], 1);
  sorted[slot] = i;
}

// ---------------- compaction: 1024 threads, ONE packed 64-bit ticket per block ----------------
// packed per-thread scan value: (parent_active << 16) | active_key_count; fields can't overflow
// (k-sum/block <= 8192, p-sum/block <= 1024). Global counter ull: hi 32 = p, lo 32 = k.
__global__ __launch_bounds__(1024) void k_plist(const int* __restrict__ cnt,
                                                float* __restrict__ m1,
                                                int* __restrict__ plist,
                                                int* __restrict__ aklist,
                                                ull_t* __restrict__ pkctr) {
  __shared__ int wsum[16];
  __shared__ ull_t sbase;
  int t = threadIdx.x;
  int p = blockIdx.x * 1024 + t;
  int lane = t & 63, wid = t >> 6;
  const int4* c4 = (const int4*)(cnt + (size_t)p*8);
  int4 a = c4[0], b = c4[1];
  int cn[8] = {a.x, a.y, a.z, a.w, b.x, b.y, b.z, b.w};
  int ck = 0;
#pragma unroll
  for (int i = 0; i < 8; i++) ck += (cn[i] > 0) ? 1 : 0;
  int pa = (ck > 0) ? 1 : 0;
  m1[p] = pa ? 1.f : 0.f;
  int packed = (pa << 16) | ck;
  int incl = packed;
#pragma unroll
  for (int o = 1; o < 64; o <<= 1) {
    int v = __shfl_up(incl, o);
    if (lane >= o) incl += v;
  }
  if (lane == 63) wsum[wid] = incl;
  __syncthreads();
  if (t == 0) {
    int tot = 0;
#pragma unroll
    for (int w = 0; w < 16; w++) { int v = wsum[w]; wsum[w] = tot; tot += v; }
    ull_t add = ((ull_t)(uint_t)(tot >> 16) << 32) | (ull_t)(uint_t)(tot & 0xffff);
    sbase = atomicAdd(pkctr, add);
  }
  __syncthreads();
  ull_t base = sbase;
  int excl = wsum[wid] + incl - packed;
  int poff = (int)(base >> 32) + (excl >> 16);
  int koff = (int)(base & 0xffffffffULL) + (excl & 0xffff);
  if (pa) plist[poff] = p;
#pragma unroll
  for (int i = 0; i < 8; i++)
    if (cn[i] > 0) aklist[koff++] = p*8 + i;
}

// ---------------- duplicate-averaging -> bf16 afeat (8 threads/key) ----------------
__global__ __launch_bounds__(256) void k_avg(const float* __restrict__ feat,
                                             const int* __restrict__ sorted,
                                             const int* __restrict__ cnt,
                                             const int* __restrict__ start,
                                             const int* __restrict__ aklist,
                                             const int* __restrict__ nactk,
                                             ushort_t* __restrict__ afb) {
  int gid = blockIdx.x * 256 + threadIdx.x;
  int j = gid >> 3;
  if (j >= nactk[0]) return;
  int key = aklist[j];
  int c = cnt[key];
  int s0 = start[key];
  int q = (gid & 7) * 4;
  float4 acc = {0.f, 0.f, 0.f, 0.f};
  for (int i = 0; i < c; i++) {
    float4 v = *(const float4*)(feat + (size_t)sorted[s0 + i] * 32 + q);
    acc.x += v.x; acc.y += v.y; acc.z += v.z; acc.w += v.w;
  }
  float inv = 1.f / (float)c;
  uint2 o;
  o.x = (uint_t)f2b(acc.x*inv) | ((uint_t)f2b(acc.y*inv) << 16);
  o.y = (uint_t)f2b(acc.z*inv) | ((uint_t)f2b(acc.w*inv) << 16);
  *(uint2*)(afb + (size_t)s0 * 32 + q) = o;
}

// ---------------- weight prep: bf16 + [chunk32][cout][32] layout ----------------
__global__ __launch_bounds__(256) void k_prepw(const float* __restrict__ w1,
                                               const float* __restrict__ w2,
                                               const float* __restrict__ w3,
                                               ushort_t* __restrict__ wt1,
                                               ushort_t* __restrict__ wt2,
                                               ushort_t* __restrict__ wt3) {
  int idx = blockIdx.x * 256 + threadIdx.x;
  if (idx < 16384) {
    int c = idx >> 11, r = idx & 2047;
    int co = r >> 5, kk = r & 31;
    wt1[idx] = f2b(w1[(c*32 + kk)*64 + co]);
  } else if (idx < 16384 + 65536) {
    int i = idx - 16384;
    int c = i >> 12, r = i & 4095;
    int co = r >> 5, kk = r & 31;
    int k = c*32 + kk;
    wt2[i] = (co < 96) ? f2b(w2[k*96 + co]) : 0;
  } else if (idx < 16384 + 65536 + 131072) {
    int i = idx - 81920;
    int c = i >> 12, r = i & 4095;
    int co = r >> 5, kk = r & 31;
    int k = c*32 + kk;
    int ch = k >> 7, ci = k & 127;
    wt3[i] = (ci < 96) ? f2b(w3[(ch*96 + ci)*128 + co]) : 0;
  }
}

// ---------------- MFMA conv1: 128 active parents x 64 couts ----------------
__global__ __launch_bounds__(256) void k_conv1m(
    const ushort_t* __restrict__ afb, const int* __restrict__ cnt,
    const int* __restrict__ start, const int* __restrict__ plist,
    const int* __restrict__ nactp, const ushort_t* __restrict__ wtg,
    ushort_t* __restrict__ x1b, float* __restrict__ sumv, float* __restrict__ sqv) {
  int nact = nactp[0];
  if (blockIdx.x * 128 >= nact) return;
  __shared__ ushort_t xs[128*40];
  __shared__ ushort_t wt[64*40];
  __shared__ int pl[128];
  __shared__ int cst[128*8];
  __shared__ float redS[4][64], redQ[4][64];
  int t = threadIdx.x;
#pragma unroll
  for (int ii = 0; ii < 4; ii++) {
    int idx = t + ii*256;
    int s = idx >> 3, ch = idx & 7;
    int gsite = blockIdx.x * 128 + s;
    bool valid = gsite < nact;
    int p = valid ? plist[gsite] : 0;
    if (ch == 0) pl[s] = p;
    int key = p*8 + ch;
    int c = valid ? cnt[key] : 0;
    cst[idx] = (c > 0) ? start[key] : -1;
  }
  int lane = t & 63, wv = t >> 6;
  int l15 = lane & 15, q = lane >> 4;
  int SB = wv * 32;
  v4f acc[2][4];
#pragma unroll
  for (int i = 0; i < 2; i++)
#pragma unroll
    for (int j = 0; j < 4; j++) acc[i][j] = (v4f){0.f, 0.f, 0.f, 0.f};
  for (int c = 0; c < 8; c++) {
    __syncthreads();
    {
      int site = t & 127, part = t >> 7;
      int sp = cst[site*8 + c];
      uint4 u0 = {0,0,0,0}, u1 = {0,0,0,0};
      if (sp >= 0) {
        const uint4* src = (const uint4*)(afb + (size_t)sp*32 + part*16);
        u0 = src[0]; u1 = src[1];
      }
      *(uint4*)&xs[site*40 + part*16]     = u0;
      *(uint4*)&xs[site*40 + part*16 + 8] = u1;
    }
    {
      uint4 w = *(const uint4*)(wtg + c*2048 + t*8);
      *(uint4*)&wt[(t >> 2)*40 + (t & 3)*8] = w;
    }
    __syncthreads();
    v8s a[2], b[4];
#pragma unroll
    for (int mt = 0; mt < 2; mt++)
      a[mt] = *(const v8s*)&xs[(SB + mt*16 + l15)*40 + q*8];
#pragma unroll
    for (int nt = 0; nt < 4; nt++)
      b[nt] = *(const v8s*)&wt[(nt*16 + l15)*40 + q*8];
#pragma unroll
    for (int mt = 0; mt < 2; mt++)
#pragma unroll
      for (int nt = 0; nt < 4; nt++)
        acc[mt][nt] = __builtin_amdgcn_mfma_f32_16x16x32_bf16(a[mt], b[nt], acc[mt][nt], 0, 0, 0);
  }
  float ss[4] = {0,0,0,0}, sq[4] = {0,0,0,0};
#pragma unroll
  for (int mt = 0; mt < 2; mt++) {
#pragma unroll
    for (int nt = 0; nt < 4; nt++) {
#pragma unroll
      for (int r = 0; r < 4; r++) {
        int sl = SB + mt*16 + q*4 + r;
        int gsite = blockIdx.x * 128 + sl;
        ushort_t h = f2b(acc[mt][nt][r]);
        float v = b2f(h);
        if (gsite < nact) x1b[(size_t)pl[sl]*64 + nt*16 + l15] = h;
        ss[nt] += v; sq[nt] += v*v;
      }
    }
  }
#pragma unroll
  for (int nt = 0; nt < 4; nt++) {
    float v1 = ss[nt], v2 = sq[nt];
    v1 += __shfl_xor(v1, 16); v1 += __shfl_xor(v1, 32);
    v2 += __shfl_xor(v2, 16); v2 += __shfl_xor(v2, 32);
    if (lane < 16) { redS[wv][nt*16 + l15] = v1; redQ[wv][nt*16 + l15] = v2; }
  }
  __syncthreads();
  if (t < 64) {
    float s = redS[0][t] + redS[1][t] + redS[2][t] + redS[3][t];
    float qq = redQ[0][t] + redQ[1][t] + redQ[2][t] + redQ[3][t];
    atomicAdd(&sumv[t], s);
    atomicAdd(&sqv[t], qq);
  }
}

// ---------------- MFMA conv (conv2/conv3): 128 sites x 128 couts ----------------
template <int CSTRIDE, int CIN_REAL, bool NINT, int DO, int HO, int WO, int DP, int HP, int WP>
__global__ __launch_bounds__(256) void k_convm(
    const ushort_t* __restrict__ xin, const float* __restrict__ mprev,
    const ushort_t* __restrict__ wtg,
    const float* __restrict__ gam, const float* __restrict__ bet,
    const float* __restrict__ ssumv, const float* __restrict__ ssqv,
    const void* __restrict__ ncnt,
    ushort_t* __restrict__ xout, float* __restrict__ osum, float* __restrict__ osq) {
  const int NCHUNK = CSTRIDE / 4;
  __shared__ ushort_t xs[128*40];
  __shared__ ushort_t wt[128*40];
  __shared__ float sc[CSTRIDE], sh[CSTRIDE];
  __shared__ int   cbase[128*8];
  __shared__ float cmask[128*8];
  __shared__ float redS[4][64], redQ[4][64];
  int t = threadIdx.x;
  if (t < CSTRIDE) {
    float scv = 0.f, shv = 0.f;
    if (t < CIN_REAL) {
      float n = NINT ? fmaxf((float)((const int*)ncnt)[0], 1.0f)
                     : fmaxf(((const float*)ncnt)[0], 1.0f);
      float mean = ssumv[t] / n;
      float var = ssqv[t] / n - mean * mean;
      float s = gam[t] * rsqrtf(var + EPS_);
      scv = s; shv = bet[t] - mean * s;
    }
    sc[t] = scv; sh[t] = shv;
  }
#pragma unroll
  for (int ii = 0; ii < 4; ii++) {
    int idx = t + ii*256;
    int s = idx >> 3, ch = idx & 7;
    int g = blockIdx.x * 128 + s;
    int b = g / (DO*HO*WO); int r = g - b*(DO*HO*WO);
    int ox = r / (HO*WO); r -= ox*(HO*WO);
    int oy = r / WO; int oz = r - oy*WO;
    int ps = ((b*DP + 2*ox + ((ch >> 2) & 1))*HP + 2*oy + ((ch >> 1) & 1))*WP + 2*oz + (ch & 1);
    cbase[idx] = ps * CSTRIDE;
    cmask[idx] = mprev[ps];
  }
  int lane = t & 63, wv = t >> 6;
  int l15 = lane & 15, q = lane >> 4;
  int SB = (wv & 1) * 64, NB = (wv >> 1) * 64;
  v4f acc[4][4];
#pragma unroll
  for (int i = 0; i < 4; i++)
#pragma unroll
    for (int j = 0; j < 4; j++) acc[i][j] = (v4f){0.f, 0.f, 0.f, 0.f};
  for (int c = 0; c < NCHUNK; c++) {
    __syncthreads();
    {
      int site = t & 127, part = t >> 7;
      int k0 = c * 32;
      int ch = k0 / CSTRIDE;
      int cio = (k0 % CSTRIDE) + part*16;
      const uint_t* src = (const uint_t*)(xin + (size_t)cbase[site*8 + ch] + cio);
      float msk = cmask[site*8 + ch];
      uint_t out[8];
#pragma unroll
      for (int u = 0; u < 8; u++) {
        uint_t w = src[u];
        int ci = cio + u*2;
        float v0 = b2f((ushort_t)(w & 0xffff));
        float v1 = b2f((ushort_t)(w >> 16));
        v0 = v0 * sc[ci] + sh[ci];     v1 = v1 * sc[ci+1] + sh[ci+1];
        v0 = (v0 > 0.f ? v0 : LEAK_*v0) * msk;
        v1 = (v1 > 0.f ? v1 : LEAK_*v1) * msk;
        out[u] = (uint_t)f2b(v0) | ((uint_t)f2b(v1) << 16);
      }
      uint4* dst = (uint4*)&xs[site*40 + part*16];
      dst[0] = make_uint4(out[0], out[1], out[2], out[3]);
      dst[1] = make_uint4(out[4], out[5], out[6], out[7]);
    }
    {
      const uint4* src = (const uint4*)(wtg + (size_t)c*4096 + t*16);
      uint4 w0 = src[0], w1 = src[1];
      uint4* dst = (uint4*)&wt[(t >> 1)*40 + (t & 1)*16];
      dst[0] = w0; dst[1] = w1;
    }
    __syncthreads();
    v8s a[4], b[4];
#pragma unroll
    for (int mt = 0; mt < 4; mt++)
      a[mt] = *(const v8s*)&xs[(SB + mt*16 + l15)*40 + q*8];
#pragma unroll
    for (int nt = 0; nt < 4; nt++)
      b[nt] = *(const v8s*)&wt[(NB + nt*16 + l15)*40 + q*8];
#pragma unroll
    for (int mt = 0; mt < 4; mt++)
#pragma unroll
      for (int nt = 0; nt < 4; nt++)
        acc[mt][nt] = __builtin_amdgcn_mfma_f32_16x16x32_bf16(a[mt], b[nt], acc[mt][nt], 0, 0, 0);
  }
  float ss[4] = {0,0,0,0}, sq[4] = {0,0,0,0};
#pragma unroll
  for (int mt = 0; mt < 4; mt++) {
#pragma unroll
    for (int nt = 0; nt < 4; nt++) {
#pragma unroll
      for (int r = 0; r < 4; r++) {
        int sl = SB + mt*16 + q*4 + r;
        size_t gsite = (size_t)blockIdx.x * 128 + sl;
        ushort_t h = f2b(acc[mt][nt][r]);
        float v = b2f(h);
        xout[gsite*128 + NB + nt*16 + l15] = h;
        ss[nt] += v; sq[nt] += v*v;
      }
    }
  }
#pragma unroll
  for (int nt = 0; nt < 4; nt++) {
    float v1 = ss[nt], v2 = sq[nt];
    v1 += __shfl_xor(v1, 16); v1 += __shfl_xor(v1, 32);
    v2 += __shfl_xor(v2, 16); v2 += __shfl_xor(v2, 32);
    if (lane < 16) { redS[wv][nt*16 + l15] = v1; redQ[wv][nt*16 + l15] = v2; }
  }
  __syncthreads();
  if (t < 128) {
    float s, qq;
    if (t < 64) { s = redS[0][t] + redS[1][t]; qq = redQ[0][t] + redQ[1][t]; }
    else        { s = redS[2][t-64] + redS[3][t-64]; qq = redQ[2][t-64] + redQ[3][t-64]; }
    atomicAdd(&osum[t], s);
    atomicAdd(&osq[t], qq);
  }
}

// ---------------- mask downsample (+ active count, 1 atomic/block) ----------------
template <int DO, int HO, int WO, int DP, int HP, int WP>
__global__ __launch_bounds__(256) void k_mask(const float* __restrict__ prev,
                                              float* __restrict__ mout,
                                              float* __restrict__ nout, int nsites) {
  __shared__ int cw[4];
  int s = blockIdx.x * 256 + threadIdx.x;
  bool act = false;
  if (s < nsites) {
    int b = s / (DO*HO*WO); int r = s - b*(DO*HO*WO);
    int ox = r / (HO*WO); r -= ox*(HO*WO);
    int oy = r / WO; int oz = r - oy*WO;
    int base = ((b*DP + 2*ox)*HP + 2*oy)*WP + 2*oz;
#pragma unroll
    for (int ch = 0; ch < 8; ch++) {
      int idx = base + ((ch >> 2) & 1)*HP*WP + ((ch >> 1) & 1)*WP + (ch & 1);
      act |= (prev[idx] > 0.0f);
    }
    mout[s] = act ? 1.0f : 0.0f;
  }
  unsigned long long bal = __ballot(act);
  if ((threadIdx.x & 63) == 0) cw[threadIdx.x >> 6] = __popcll(bal);
  __syncthreads();
  if (threadIdx.x == 0)
    atomicAdd(nout, (float)(cw[0] + cw[1] + cw[2] + cw[3]));
}

// ---------------- final conv (cout=1) + sigmoid + mask ----------------
__global__ __launch_bounds__(256) void k_final(
    const ushort_t* __restrict__ x3b, const float* __restrict__ m3,
    const float* __restrict__ w4, const float* __restrict__ gam,
    const float* __restrict__ bet, const float* __restrict__ ssumv,
    const float* __restrict__ ssqv, const float* __restrict__ ncnt,
    float* __restrict__ out) {
  __shared__ float sc[128], sh[128];
  __shared__ int cb[8];
  __shared__ float msk[8];
  __shared__ float red[256];
  int t = threadIdx.x;
  if (t < 128) {
    float n = fmaxf(ncnt[0], 1.0f);
    float mean = ssumv[t] / n;
    float var = ssqv[t] / n - mean * mean;
    float s = gam[t] * rsqrtf(var + EPS_);
    sc[t] = s; sh[t] = bet[t] - mean * s;
  }
  int g = blockIdx.x;
  int b = g / (D4*H4*W4); int r = g - b*(D4*H4*W4);
  int ox = r / (H4*W4); r -= ox*(H4*W4);
  int oy = r / W4; int oz = r - oy*W4;
  if (t < 8) {
    int ps = ((b*D3 + 2*ox + ((t >> 2) & 1))*H3 + 2*oy + ((t >> 1) & 1))*W3 + 2*oz + (t & 1);
    cb[t] = ps * 128;
    msk[t] = m3[ps];
  }
  __syncthreads();
  float acc = 0.f;
#pragma unroll
  for (int ii = 0; ii < 4; ii++) {
    int k = t + ii*256;
    int ch = k >> 7, ci = k & 127;
    float v = b2f(x3b[cb[ch] + ci]);
    v = v * sc[ci] + sh[ci];
    v = (v > 0.f ? v : LEAK_ * v) * msk[ch];
    acc += v * w4[k];
  }
  red[t] = acc;
  __syncthreads();
  if (t < 128) red[t] += red[t + 128];
  __syncthreads();
  if (t < 64) {
    float v = red[t] + red[t + 64];
#pragma unroll
    for (int off = 32; off > 0; off >>= 1) v += __shfl_down(v, off);
    if (t == 0) {
      float any = (msk[0] + msk[1] + msk[2] + msk[3] + msk[4] + msk[5] + msk[6] + msk[7]) > 0.f ? 1.f : 0.f;
      out[g] = any / (1.0f + expf(-v));
    }
  }
}

extern "C" void kernel_launch(void* const* d_in, const int* in_sizes, int n_in,
                              void* d_out, int out_size, void* d_ws, size_t ws_size,
                              hipStream_t stream) {
  (void)in_sizes; (void)n_in; (void)out_size; (void)ws_size;
  const float* feat = (const float*)d_in[0];
  const int*   crd  = (const int*)d_in[1];
  const float* w1 = (const float*)d_in[2];
  const float* g1 = (const float*)d_in[3];
  const float* b1 = (const float*)d_in[4];
  const float* w2 = (const float*)d_in[5];
  const float* g2 = (const float*)d_in[6];
  const float* b2 = (const float*)d_in[7];
  const float* w3 = (const float*)d_in[8];
  const float* g3 = (const float*)d_in[9];
  const float* b3 = (const float*)d_in[10];
  const float* w4 = (const float*)d_in[11];
  float* out = (float*)d_out;
  float* ws  = (float*)d_ws;

  int*      cnt    = (int*)(ws + OFF_CNT);
  float*    st     = ws + OFF_STATS;
  int*      start  = (int*)(ws + OFF_START);
  int*      sorted = (int*)(ws + OFF_SORTED);
  int*      aklist = (int*)(ws + OFF_AKLIST);
  int*      plist  = (int*)(ws + OFF_PLIST);
  ushort_t* wt1g   = (ushort_t*)(ws + OFF_WT1);
  ushort_t* wt2g   = (ushort_t*)(ws + OFF_WT2);
  ushort_t* wt3g   = (ushort_t*)(ws + OFF_WT3);
  ushort_t* afb    = (ushort_t*)(ws + OFF_AFEATB);
  ushort_t* x1b    = (ushort_t*)(ws + OFF_X1B);
  int*      cursor = (int*)(ws + OFF_X1B);   // overlays x1b head; dead after k_scatter
  ushort_t* x2b    = (ushort_t*)(ws + OFF_X2B);
  ushort_t* x3b    = (ushort_t*)(ws + OFF_X3B);
  float*    m1     = ws + OFF_M1;
  float*    m2     = ws + OFF_M2;
  float*    m3     = ws + OFF_M3;
  // packed ticket counter: ull at st+644 (lo 32 = nactk, hi 32 = nactp)
  ull_t*    pkctr  = (ull_t*)(st + 644);
  int*      nactk  = (int*)(st + 644);
  int*      nactp  = (int*)(st + 645);

  hipMemsetAsync(d_ws, 0, (size_t)(OFF_STATS + 1024) * sizeof(float), stream);

  k_count<<<(PNUM + 255) / 256, 256, 0, stream>>>(crd, cnt);
  k_alloc<<<NVOX / 4096, 1024, 0, stream>>>(cnt, start, cursor, (int*)(st + 643));
  k_scatter<<<(PNUM + 255) / 256, 256, 0, stream>>>(crd, cursor, sorted);
  k_plist<<<N1S / 1024, 1024, 0, stream>>>(cnt, m1, plist, aklist, pkctr);
  k_avg<<<(PNUM * 8) / 256 + 1, 256, 0, stream>>>(feat, sorted, cnt, start, aklist,
                                                  nactk, afb);
  k_prepw<<<(16384 + 65536 + 131072) / 256, 256, 0, stream>>>(w1, w2, w3, wt1g, wt2g, wt3g);
  hipMemsetAsync(x1b, 0, (size_t)N1S * 64 * sizeof(ushort_t), stream);
  k_conv1m<<<(N1S + 127) / 128, 256, 0, stream>>>(afb, cnt, start, plist,
                                                  nactp, wt1g, x1b, st + 0, st + 64);
  k_mask<D2,H2,W2, D1,H1,W1><<<N2S / 256, 256, 0, stream>>>(m1, m2, st + 641, N2S);
  k_convm<64, 64, true, D2,H2,W2, D1,H1,W1><<<N2S / 128, 256, 0, stream>>>(
      x1b, m1, wt2g, g1, b1, st + 0, st + 64, (const void*)nactp, x2b, st + 128, st + 256);
  k_mask<D3,H3,W3, D2,H2,W2><<<(N3S + 255) / 256, 256, 0, stream>>>(m2, m3, st + 642, N3S);
  k_convm<128, 96, false, D3,H3,W3, D2,H2,W2><<<N3S / 128, 256, 0, stream>>>(
      x2b, m2, wt3g, g2, b2, st + 128, st + 256, (const void*)(st + 641), x3b, st + 384, st + 512);
  k_final<<<N4S, 256, 0, stream>>>(x3b, m3, w4, g3, b3, st + 384, st + 512, st + 642, out);
}